// Round 1
// baseline (1875.130 us; speedup 1.0000x reference)
//
#include <hip/hip_runtime.h>

#define NTOT 21904
#define NPATCH 1369
#define BIMG 16
#define DIM 768
#define NCLS 200
#define CDIM 201
#define KP 5
#define NCK 1005

__device__ __forceinline__ unsigned encf(float x){
  unsigned b = __float_as_uint(x);
  return (b & 0x80000000u) ? ~b : (b | 0x80000000u);
}
__device__ __forceinline__ float decf(unsigned e){
  return (e & 0x80000000u) ? __uint_as_float(e ^ 0x80000000u) : __uint_as_float(~e);
}

__device__ __forceinline__ float red256(float v, float* sh){
  int t = threadIdx.x;
  sh[t] = v; __syncthreads();
  for(int s = 128; s > 0; s >>= 1){ if(t < s) sh[t] += sh[t+s]; __syncthreads(); }
  float r = sh[0]; __syncthreads();
  return r;
}

// ---------------- init ----------------
__global__ void k_init(int* counts, unsigned* enc){
  int t = threadIdx.x;
  if(t < CDIM) counts[t] = 0;
  if(t == 0){ enc[0] = 0xFFFFFFFFu; enc[1] = 0u; }
}

// ---------------- column mean, stage 1 (deterministic two-stage) ----------------
__global__ __launch_bounds__(256) void k_colmean1(const float* __restrict__ X, float* __restrict__ pbuf){
  int col = blockIdx.x * 256 + threadIdx.x;   // grid.x = 3
  int chunk = blockIdx.y;                     // 32 chunks
  int n0 = chunk * 685; int n1 = n0 + 685; if(n1 > NTOT) n1 = NTOT;
  float s = 0.f;
  for(int n = n0; n < n1; ++n) s += X[(size_t)n * DIM + col];
  pbuf[chunk * DIM + col] = s;
}

__global__ __launch_bounds__(768) void k_meanfin(const float* __restrict__ pbuf, float* __restrict__ meanv,
                                                 float* __restrict__ vvec, float* __restrict__ scal){
  __shared__ float sh[1024];
  int t = threadIdx.x;
  float s = 0.f;
  for(int c = 0; c < 32; ++c) s += pbuf[c * DIM + t];
  float m = s / 21904.0f;
  meanv[t] = m;
  float v0 = 1.0f / sqrtf(768.0f);
  vvec[t] = v0;
  sh[t] = m * v0; if(t < 256) sh[768 + t] = 0.f; __syncthreads();
  for(int st = 512; st > 0; st >>= 1){ if(t < st) sh[t] += sh[t+st]; __syncthreads(); }
  if(t == 0) scal[0] = sh[0];  // mv = dot(mean, v)
}

// ---------------- fused power-iteration pass: vraw = Xc^T (Xc v) ----------------
__global__ __launch_bounds__(256) void k_pcapass(const float* __restrict__ X,
    const float* __restrict__ vvec, const float* __restrict__ scal,
    float* __restrict__ pbuf, float* __restrict__ subuf){
  __shared__ float shacc[4][DIM];
  __shared__ float shsu[4];
  int t = threadIdx.x, w = t >> 6, l = t & 63;
  float mv = scal[0];
  const float4* v4 = (const float4*)(vvec + l * 12);
  float4 v0 = v4[0], v1 = v4[1], v2 = v4[2];
  float4 a0 = {0,0,0,0}, a1 = {0,0,0,0}, a2 = {0,0,0,0};
  float su = 0.f;
  for(int n = blockIdx.x * 4 + w; n < NTOT; n += 1024){
    const float4* x4 = (const float4*)(X + (size_t)n * DIM + l * 12);
    float4 x0 = x4[0], x1 = x4[1], x2 = x4[2];
    float tp = x0.x*v0.x + x0.y*v0.y + x0.z*v0.z + x0.w*v0.w
             + x1.x*v1.x + x1.y*v1.y + x1.z*v1.z + x1.w*v1.w
             + x2.x*v2.x + x2.y*v2.y + x2.z*v2.z + x2.w*v2.w;
    #pragma unroll
    for(int o = 32; o > 0; o >>= 1) tp += __shfl_xor(tp, o);
    tp -= mv;
    a0.x += tp*x0.x; a0.y += tp*x0.y; a0.z += tp*x0.z; a0.w += tp*x0.w;
    a1.x += tp*x1.x; a1.y += tp*x1.y; a1.z += tp*x1.z; a1.w += tp*x1.w;
    a2.x += tp*x2.x; a2.y += tp*x2.y; a2.z += tp*x2.z; a2.w += tp*x2.w;
    if(l == 0) su += tp;
  }
  float4* sh4 = (float4*)&shacc[w][l * 12];
  sh4[0] = a0; sh4[1] = a1; sh4[2] = a2;
  if(l == 0) shsu[w] = su;
  __syncthreads();
  for(int c = t; c < DIM; c += 256)
    pbuf[blockIdx.x * DIM + c] = shacc[0][c] + shacc[1][c] + shacc[2][c] + shacc[3][c];
  if(t == 0) subuf[blockIdx.x] = shsu[0] + shsu[1] + shsu[2] + shsu[3];
}

__global__ __launch_bounds__(768) void k_pcanorm(const float* __restrict__ pbuf,
    const float* __restrict__ subuf, const float* __restrict__ meanv,
    float* __restrict__ vvec, float* __restrict__ scal){
  __shared__ float sh[1024];
  int t = threadIdx.x;
  sh[t] = (t < 256) ? subuf[t] : 0.f;
  if(t < 256) sh[768 + t] = 0.f;
  __syncthreads();
  for(int st = 512; st > 0; st >>= 1){ if(t < st) sh[t] += sh[t+st]; __syncthreads(); }
  float su = sh[0]; __syncthreads();
  float s = 0.f;
  for(int b2 = 0; b2 < 256; ++b2) s += pbuf[b2 * DIM + t];
  float wv = s - meanv[t] * su;
  sh[t] = wv * wv; if(t < 256) sh[768 + t] = 0.f; __syncthreads();
  for(int st = 512; st > 0; st >>= 1){ if(t < st) sh[t] += sh[t+st]; __syncthreads(); }
  float nrm = sqrtf(sh[0]); __syncthreads();
  float nv = wv / (nrm + 1e-12f);
  vvec[t] = nv;
  sh[t] = meanv[t] * nv; if(t < 256) sh[768 + t] = 0.f; __syncthreads();
  for(int st = 512; st > 0; st >>= 1){ if(t < st) sh[t] += sh[t+st]; __syncthreads(); }
  if(t == 0) scal[0] = sh[0];  // mv for next pass
}

// ---------------- final u = Xc v, plus min/max ----------------
__global__ __launch_bounds__(256) void k_ufinal(const float* __restrict__ X,
    const float* __restrict__ vvec, const float* __restrict__ scal,
    float* __restrict__ u, unsigned* __restrict__ enc){
  __shared__ float smn[4], smx[4];
  int t = threadIdx.x, w = t >> 6, l = t & 63;
  float mv = scal[0];
  const float4* v4 = (const float4*)(vvec + l * 12);
  float4 v0 = v4[0], v1 = v4[1], v2 = v4[2];
  float lmn = 3.4e38f, lmx = -3.4e38f;
  for(int n = blockIdx.x * 4 + w; n < NTOT; n += 1024){
    const float4* x4 = (const float4*)(X + (size_t)n * DIM + l * 12);
    float4 x0 = x4[0], x1 = x4[1], x2 = x4[2];
    float tp = x0.x*v0.x + x0.y*v0.y + x0.z*v0.z + x0.w*v0.w
             + x1.x*v1.x + x1.y*v1.y + x1.z*v1.z + x1.w*v1.w
             + x2.x*v2.x + x2.y*v2.y + x2.z*v2.z + x2.w*v2.w;
    #pragma unroll
    for(int o = 32; o > 0; o >>= 1) tp += __shfl_xor(tp, o);
    tp -= mv;
    if(l == 0){ u[n] = tp; lmn = fminf(lmn, tp); lmx = fmaxf(lmx, tp); }
  }
  if(l == 0){ smn[w] = lmn; smx[w] = lmx; }
  __syncthreads();
  if(t == 0){
    float mn = fminf(fminf(smn[0], smn[1]), fminf(smn[2], smn[3]));
    float mx = fmaxf(fmaxf(smx[0], smx[1]), fmaxf(smx[2], smx[3]));
    atomicMin(&enc[0], encf(mn));
    atomicMax(&enc[1], encf(mx));
  }
}

// ---------------- pseudo labels ----------------
__global__ __launch_bounds__(256) void k_pseudo(const float* __restrict__ u,
    const unsigned* __restrict__ enc, const int* __restrict__ labels,
    int* __restrict__ pl, float* __restrict__ pseudo_out,
    float* __restrict__ assign_out, int* __restrict__ counts){
  int n = blockIdx.x * 256 + threadIdx.x;
  if(n >= NTOT) return;
  float mn = decf(enc[0]), mx = decf(enc[1]);
  float us = (u[n] - mn) / (mx - mn);
  int b = n / NPATCH;
  int p = (us <= 0.5f) ? labels[b] : NCLS;
  pl[n] = p;
  pseudo_out[n] = (float)p;
  assign_out[n] = -1.0f;
  atomicAdd(&counts[p], 1);
}

__global__ void k_rank(const int* __restrict__ counts, int* __restrict__ rankv){
  if(threadIdx.x == 0){
    int r = 0;
    for(int c = 0; c < NCLS; ++c){
      if(counts[c] > 0){ rankv[c] = r; r++; } else rankv[c] = 0;
    }
  }
}

// ---------------- row norms ----------------
__global__ __launch_bounds__(256) void k_rnorm(const float* __restrict__ X, float* __restrict__ rinv){
  int t = threadIdx.x, w = t >> 6, l = t & 63;
  int n = blockIdx.x * 4 + w;
  if(n >= NTOT) return;
  const float4* x4 = (const float4*)(X + (size_t)n * DIM + l * 12);
  float4 x0 = x4[0], x1 = x4[1], x2 = x4[2];
  float s = x0.x*x0.x + x0.y*x0.y + x0.z*x0.z + x0.w*x0.w
          + x1.x*x1.x + x1.y*x1.y + x1.z*x1.z + x1.w*x1.w
          + x2.x*x2.x + x2.y*x2.y + x2.z*x2.z + x2.w*x2.w;
  #pragma unroll
  for(int o = 32; o > 0; o >>= 1) s += __shfl_xor(s, o);
  if(l == 0) rinv[n] = 1.0f / (sqrtf(s) + 1e-12f);
}

// ---------------- normalized prototypes + bias2 = b . protn ----------------
__global__ __launch_bounds__(256) void k_protn(const float* __restrict__ P,
    const float* __restrict__ bvec, float* __restrict__ protn, float* __restrict__ bias2){
  int t = threadIdx.x, w = t >> 6, l = t & 63;
  int r = blockIdx.x * 4 + w;
  if(r >= NCK) return;
  const float4* x4 = (const float4*)(P + (size_t)r * DIM + l * 12);
  float4 x0 = x4[0], x1 = x4[1], x2 = x4[2];
  float s = x0.x*x0.x + x0.y*x0.y + x0.z*x0.z + x0.w*x0.w
          + x1.x*x1.x + x1.y*x1.y + x1.z*x1.z + x1.w*x1.w
          + x2.x*x2.x + x2.y*x2.y + x2.z*x2.z + x2.w*x2.w;
  #pragma unroll
  for(int o = 32; o > 0; o >>= 1) s += __shfl_xor(s, o);
  float rv = 1.0f / (sqrtf(s) + 1e-12f);
  x0.x *= rv; x0.y *= rv; x0.z *= rv; x0.w *= rv;
  x1.x *= rv; x1.y *= rv; x1.z *= rv; x1.w *= rv;
  x2.x *= rv; x2.y *= rv; x2.z *= rv; x2.w *= rv;
  float4* o4 = (float4*)(protn + (size_t)r * DIM + l * 12);
  o4[0] = x0; o4[1] = x1; o4[2] = x2;
  const float4* b4 = (const float4*)(bvec + l * 12);
  float4 b0 = b4[0], b1 = b4[1], b2 = b4[2];
  float bb = b0.x*x0.x + b0.y*x0.y + b0.z*x0.z + b0.w*x0.w
           + b1.x*x1.x + b1.y*x1.y + b1.z*x1.z + b1.w*x1.w
           + b2.x*x2.x + b2.y*x2.y + b2.z*x2.z + b2.w*x2.w;
  #pragma unroll
  for(int o = 32; o > 0; o >>= 1) bb += __shfl_xor(bb, o);
  if(l == 0) bias2[r] = bb;
}

// ---------------- NT GEMM: C[M,N] = A[M,K] * B[N,K]^T (+ scale/bias/add) ----------------
template<int HAS_SCALE, int HAS_BIAS, int HAS_ADD>
__global__ __launch_bounds__(256) void k_gemm_nt(const float* __restrict__ A,
    const float* __restrict__ B, float* __restrict__ C,
    const float* __restrict__ rowScale, const float* __restrict__ colBias,
    const float* __restrict__ addMat, int M, int N, int K){
  __shared__ float As[32][72];
  __shared__ float Bs[32][72];
  int t = threadIdx.x;
  int m0 = blockIdx.y * 64, n0 = blockIdx.x * 64;
  int srow = t >> 2, skq = (t & 3) * 8;
  int ty = t >> 4, tx = t & 15;
  int i0 = ty * 4, j0 = tx * 4;
  float acc[4][4] = {};
  int gra = m0 + srow; bool va = gra < M;
  int grb = n0 + srow; bool vb = grb < N;
  float scale = 1.0f;
  if(HAS_SCALE && va) scale = rowScale[gra];
  const float* Aptr = A + (size_t)gra * K + skq;
  const float* Bptr = B + (size_t)grb * K + skq;
  for(int k0 = 0; k0 < K; k0 += 32){
    float4 a0 = {0,0,0,0}, a1 = {0,0,0,0}, b0 = {0,0,0,0}, b1 = {0,0,0,0};
    if(va){ a0 = *(const float4*)(Aptr + k0); a1 = *(const float4*)(Aptr + k0 + 4); }
    if(vb){ b0 = *(const float4*)(Bptr + k0); b1 = *(const float4*)(Bptr + k0 + 4); }
    if(HAS_SCALE){
      a0.x *= scale; a0.y *= scale; a0.z *= scale; a0.w *= scale;
      a1.x *= scale; a1.y *= scale; a1.z *= scale; a1.w *= scale;
    }
    __syncthreads();
    As[skq+0][srow] = a0.x; As[skq+1][srow] = a0.y; As[skq+2][srow] = a0.z; As[skq+3][srow] = a0.w;
    As[skq+4][srow] = a1.x; As[skq+5][srow] = a1.y; As[skq+6][srow] = a1.z; As[skq+7][srow] = a1.w;
    Bs[skq+0][srow] = b0.x; Bs[skq+1][srow] = b0.y; Bs[skq+2][srow] = b0.z; Bs[skq+3][srow] = b0.w;
    Bs[skq+4][srow] = b1.x; Bs[skq+5][srow] = b1.y; Bs[skq+6][srow] = b1.z; Bs[skq+7][srow] = b1.w;
    __syncthreads();
    #pragma unroll
    for(int kk = 0; kk < 32; ++kk){
      float4 avv = *(const float4*)&As[kk][i0];
      float4 bvv = *(const float4*)&Bs[kk][j0];
      float a_[4] = {avv.x, avv.y, avv.z, avv.w};
      float b_[4] = {bvv.x, bvv.y, bvv.z, bvv.w};
      #pragma unroll
      for(int i = 0; i < 4; ++i)
        #pragma unroll
        for(int j = 0; j < 4; ++j)
          acc[i][j] += a_[i] * b_[j];
    }
  }
  #pragma unroll
  for(int i = 0; i < 4; ++i){
    int gr = m0 + i0 + i; if(gr >= M) continue;
    #pragma unroll
    for(int j = 0; j < 4; ++j){
      int gc = n0 + j0 + j; if(gc >= N) continue;
      float v2 = acc[i][j];
      if(HAS_BIAS) v2 += colBias[gc];
      if(HAS_ADD) v2 += addMat[(size_t)gr * N + gc];
      C[(size_t)gr * N + gc] = v2;
    }
  }
}

// ---------------- per-class masked Sinkhorn ----------------
__global__ __launch_bounds__(256) void k_sinkhorn(const float* __restrict__ logits,
    const int* __restrict__ pl, const int* __restrict__ counts, const int* __restrict__ rankv,
    const int* __restrict__ labels, float* __restrict__ Aw, float* __restrict__ assign_out){
  int c = blockIdx.x;
  int NcI = counts[c];
  if(NcI == 0) return;
  __shared__ int imgs[BIMG];
  __shared__ int nimgS;
  __shared__ float sh[256];
  int t = threadIdx.x;
  if(t == 0){
    int ni = 0;
    for(int b = 0; b < BIMG; ++b) if(labels[b] == c) imgs[ni++] = b;
    nimgS = ni;
  }
  __syncthreads();
  int tot = nimgS * NPATCH;
  float Ncf = (float)NcI;
  float invNc = 1.0f / Ncf;

  // phase 0: exp + total sum
  float sp = 0.f;
  for(int ii = t; ii < tot; ii += 256){
    int n = imgs[ii / NPATCH] * NPATCH + (ii % NPATCH);
    if(pl[n] != c) continue;
    const float* lg = logits + (size_t)n * NCK + c * KP;
    float* aw = Aw + (size_t)n * KP;
    float l0 = expf(lg[0] / 0.05f), l1 = expf(lg[1] / 0.05f), l2 = expf(lg[2] / 0.05f),
          l3 = expf(lg[3] / 0.05f), l4 = expf(lg[4] / 0.05f);
    aw[0] = l0; aw[1] = l1; aw[2] = l2; aw[3] = l3; aw[4] = l4;
    sp += l0 + l1 + l2 + l3 + l4;
  }
  float S = red256(sp, sh);
  float sc = 1.0f / (S + 1e-16f);

  // scale + first column sums
  float cs0 = 0, cs1 = 0, cs2 = 0, cs3 = 0, cs4 = 0;
  for(int ii = t; ii < tot; ii += 256){
    int n = imgs[ii / NPATCH] * NPATCH + (ii % NPATCH);
    if(pl[n] != c) continue;
    float* aw = Aw + (size_t)n * KP;
    float l0 = aw[0]*sc, l1 = aw[1]*sc, l2 = aw[2]*sc, l3 = aw[3]*sc, l4 = aw[4]*sc;
    aw[0] = l0; aw[1] = l1; aw[2] = l2; aw[3] = l3; aw[4] = l4;
    cs0 += l0; cs1 += l1; cs2 += l2; cs3 += l3; cs4 += l4;
  }
  cs0 = red256(cs0, sh); cs1 = red256(cs1, sh); cs2 = red256(cs2, sh);
  cs3 = red256(cs3, sh); cs4 = red256(cs4, sh);

  for(int it = 0; it < 3; ++it){
    float m0 = 1.0f/(cs0+1e-16f), m1 = 1.0f/(cs1+1e-16f), m2 = 1.0f/(cs2+1e-16f),
          m3 = 1.0f/(cs3+1e-16f), m4 = 1.0f/(cs4+1e-16f);
    bool last = (it == 2);
    float n0 = 0, n1 = 0, n2 = 0, n3 = 0, n4 = 0;
    for(int ii = t; ii < tot; ii += 256){
      int n = imgs[ii / NPATCH] * NPATCH + (ii % NPATCH);
      if(pl[n] != c) continue;
      float* aw = Aw + (size_t)n * KP;
      float l0 = aw[0]*m0*0.2f, l1 = aw[1]*m1*0.2f, l2 = aw[2]*m2*0.2f,
            l3 = aw[3]*m3*0.2f, l4 = aw[4]*m4*0.2f;
      float rs = l0 + l1 + l2 + l3 + l4;
      float rw = 1.0f / (rs + 1e-16f);
      if(last){
        // row scale /Nc then final *Nc cancel
        l0 *= rw; l1 *= rw; l2 *= rw; l3 *= rw; l4 *= rw;
        aw[0] = l0; aw[1] = l1; aw[2] = l2; aw[3] = l3; aw[4] = l4;
        int am = 0; float bv = l0;
        if(l1 > bv){ bv = l1; am = 1; }
        if(l2 > bv){ bv = l2; am = 2; }
        if(l3 > bv){ bv = l3; am = 3; }
        if(l4 > bv){ bv = l4; am = 4; }
        assign_out[n] = (float)(am + KP * rankv[c]);
      } else {
        float w2 = rw * invNc;
        l0 *= w2; l1 *= w2; l2 *= w2; l3 *= w2; l4 *= w2;
        aw[0] = l0; aw[1] = l1; aw[2] = l2; aw[3] = l3; aw[4] = l4;
        n0 += l0; n1 += l1; n2 += l2; n3 += l3; n4 += l4;
      }
    }
    if(!last){
      cs0 = red256(n0, sh); cs1 = red256(n1, sh); cs2 = red256(n2, sh);
      cs3 = red256(n3, sh); cs4 = red256(n4, sh);
    }
  }
}

// ---------------- P_new + EMA ----------------
__global__ __launch_bounds__(256) void k_pnew(const float* __restrict__ P,
    const float* __restrict__ X, const float* __restrict__ rinv,
    const float* __restrict__ Aw, const int* __restrict__ pl,
    const int* __restrict__ counts, const int* __restrict__ labels,
    float* __restrict__ out_np){
  int c = blockIdx.x;
  int t = threadIdx.x;
  bool pres = (c < NCLS) && (counts[c] > 0);
  if(!pres){
    for(int i = t; i < KP * DIM; i += 256)
      out_np[(size_t)c * KP * DIM + i] = P[(size_t)c * KP * DIM + i];
    return;
  }
  int imgs[BIMG]; int ni = 0;
  for(int b = 0; b < BIMG; ++b) if(labels[b] == c) imgs[ni++] = b;
  float acc[3][5] = {};
  for(int q = 0; q < ni; ++q){
    int base = imgs[q] * NPATCH;
    for(int j = 0; j < NPATCH; ++j){
      int n = base + j;
      if(pl[n] != c) continue;
      const float* aw = Aw + (size_t)n * KP;
      float a0 = aw[0], a1 = aw[1], a2 = aw[2], a3 = aw[3], a4 = aw[4];
      float rv = rinv[n];
      #pragma unroll
      for(int dj = 0; dj < 3; ++dj){
        float x = X[(size_t)n * DIM + t + dj * 256] * rv;
        acc[dj][0] += a0 * x; acc[dj][1] += a1 * x; acc[dj][2] += a2 * x;
        acc[dj][3] += a3 * x; acc[dj][4] += a4 * x;
      }
    }
  }
  #pragma unroll
  for(int dj = 0; dj < 3; ++dj)
    #pragma unroll
    for(int k = 0; k < 5; ++k){
      size_t o = ((size_t)c * KP + k) * DIM + t + dj * 256;
      out_np[o] = 0.99f * P[o] + 0.01f * acc[dj][k];
    }
}

// ---------------- pooled = logits.mean(axis=1) ----------------
__global__ __launch_bounds__(256) void k_pooled(const float* __restrict__ logits, float* __restrict__ pooled){
  int c = blockIdx.x;  // 0..200
  int b = blockIdx.y;  // 0..15
  int t = threadIdx.x;
  float a0 = 0, a1 = 0, a2 = 0, a3 = 0, a4 = 0;
  for(int n = t; n < NPATCH; n += 256){
    const float* p = logits + ((size_t)(b * NPATCH + n)) * NCK + c * KP;
    a0 += p[0]; a1 += p[1]; a2 += p[2]; a3 += p[3]; a4 += p[4];
  }
  __shared__ float sh[256];
  a0 = red256(a0, sh); a1 = red256(a1, sh); a2 = red256(a2, sh);
  a3 = red256(a3, sh); a4 = red256(a4, sh);
  if(t == 0){
    float* o = pooled + (size_t)b * NCK + c * KP;
    o[0] = a0 / 1369.0f; o[1] = a1 / 1369.0f; o[2] = a2 / 1369.0f;
    o[3] = a3 / 1369.0f; o[4] = a4 / 1369.0f;
  }
}

// ---------------- class logits (sa head) ----------------
__global__ __launch_bounds__(256) void k_cls(const float* __restrict__ pooled,
    const float* __restrict__ sa, float* __restrict__ out){
  int b = blockIdx.x;
  int i = threadIdx.x;
  if(i >= NCLS) return;
  float s0 = sa[i*5+0], s1 = sa[i*5+1], s2 = sa[i*5+2], s3 = sa[i*5+3], s4 = sa[i*5+4];
  float mx = fmaxf(fmaxf(fmaxf(s0, s1), fmaxf(s2, s3)), s4);
  float e0 = expf(s0 - mx), e1 = expf(s1 - mx), e2 = expf(s2 - mx),
        e3 = expf(s3 - mx), e4 = expf(s4 - mx);
  float se = e0 + e1 + e2 + e3 + e4;
  float iv = 5.0f / se;
  const float* p = pooled + (size_t)b * NCK + i * KP;
  float cl = p[0]*e0*iv + p[1]*e1*iv + p[2]*e2*iv + p[3]*e3*iv + p[4]*e4*iv;
  out[b * NCLS + i] = cl;
}

extern "C" void kernel_launch(void* const* d_in, const int* in_sizes, int n_in,
                              void* d_out, int out_size, void* d_ws, size_t ws_size,
                              hipStream_t stream){
  const float* X      = (const float*)d_in[0];   // patch_tokens [16,1369,768]
  const int*   labels = (const int*)d_in[1];     // [16]
  const float* P      = (const float*)d_in[2];   // prototypes [201,5,768]
  const float* W      = (const float*)d_in[3];   // [768,768]
  const float* bvec   = (const float*)d_in[4];   // [768]
  const float* sa     = (const float*)d_in[5];   // [200,5]

  float* out        = (float*)d_out;
  float* out_cls    = out;                                  // 3200
  float* out_logits = out + 3200;                           // 22013880
  float* out_pooled = out_logits + (size_t)NTOT * NCK;      // 16080
  float* out_assign = out_pooled + BIMG * NCK;              // 21904
  float* out_np     = out_assign + NTOT;                    // 771840
  float* out_pseudo = out_np + (size_t)CDIM * KP * DIM;     // 21904

  float* ws     = (float*)d_ws;
  float* protn  = ws;                                  // 1005*768
  float* Bmat   = protn + (size_t)NCK * DIM;           // 1005*768
  float* bias2  = Bmat + (size_t)NCK * DIM;            // 1024
  float* rinv   = bias2 + 1024;                        // 21904
  float* uvec   = rinv + NTOT;                         // 21904
  float* Aw     = uvec + NTOT;                         // 21904*5
  float* meanv  = Aw + (size_t)NTOT * KP;              // 768
  float* vvec   = meanv + DIM;                         // 768
  float* pbuf   = vvec + DIM;                          // 256*768
  float* subuf  = pbuf + 256 * DIM;                    // 256
  float* scal   = subuf + 256;                         // 8 (mv, enc_min, enc_max)
  int*   pli    = (int*)(scal + 8);                    // 21904
  int*   counts = pli + NTOT;                          // 256
  int*   rankv  = counts + 256;                        // 256
  unsigned* enc = (unsigned*)(scal + 1);

  k_init<<<1, 256, 0, stream>>>(counts, enc);
  k_colmean1<<<dim3(3, 32), 256, 0, stream>>>(X, pbuf);
  k_meanfin<<<1, 768, 0, stream>>>(pbuf, meanv, vvec, scal);
  for(int i = 0; i < 10; ++i){
    k_pcapass<<<256, 256, 0, stream>>>(X, vvec, scal, pbuf, subuf);
    k_pcanorm<<<1, 768, 0, stream>>>(pbuf, subuf, meanv, vvec, scal);
  }
  k_ufinal<<<256, 256, 0, stream>>>(X, vvec, scal, uvec, enc);
  k_pseudo<<<86, 256, 0, stream>>>(uvec, enc, labels, pli, out_pseudo, out_assign, counts);
  k_rank<<<1, 64, 0, stream>>>(counts, rankv);
  k_rnorm<<<5476, 256, 0, stream>>>(X, rinv);
  k_protn<<<252, 256, 0, stream>>>(P, bvec, protn, bias2);
  // BmatT[r,e] = protn[r,e] + sum_d W[e,d]*protn[r,d]
  k_gemm_nt<0, 0, 1><<<dim3(12, 16), 256, 0, stream>>>(protn, W, Bmat, nullptr, nullptr, protn, NCK, DIM, DIM);
  // logits[n,ck] = sum_e ptn[n,e]*BmatT[ck,e] + bias2[ck]
  k_gemm_nt<1, 1, 0><<<dim3(16, 343), 256, 0, stream>>>(X, Bmat, out_logits, rinv, bias2, nullptr, NTOT, NCK, DIM);
  k_sinkhorn<<<NCLS, 256, 0, stream>>>(out_logits, pli, counts, rankv, labels, Aw, out_assign);
  k_pnew<<<CDIM, 256, 0, stream>>>(P, X, rinv, Aw, pli, counts, labels, out_np);
  k_pooled<<<dim3(CDIM, BIMG), 256, 0, stream>>>(out_logits, out_pooled);
  k_cls<<<BIMG, 256, 0, stream>>>(out_pooled, sa, out_cls);
}

// Round 2
// 1218.784 us; speedup vs baseline: 1.5385x; 1.5385x over previous
//
#include <hip/hip_runtime.h>

#define NTOT 21904
#define NPATCH 1369
#define BIMG 16
#define DIM 768
#define NCLS 200
#define CDIM 201
#define KP 5
#define NCK 1005
#define PCH 16   // pnew patch chunks per image
#define QCH 32   // pool patch chunks per image

__device__ __forceinline__ unsigned encf(float x){
  unsigned b = __float_as_uint(x);
  return (b & 0x80000000u) ? ~b : (b | 0x80000000u);
}
__device__ __forceinline__ float decf(unsigned e){
  return (e & 0x80000000u) ? __uint_as_float(e ^ 0x80000000u) : __uint_as_float(~e);
}

__device__ __forceinline__ float red256(float v, float* sh){
  int t = threadIdx.x;
  sh[t] = v; __syncthreads();
  for(int s = 128; s > 0; s >>= 1){ if(t < s) sh[t] += sh[t+s]; __syncthreads(); }
  float r = sh[0]; __syncthreads();
  return r;
}

// ---------------- init ----------------
__global__ void k_init(int* counts, unsigned* enc){
  int t = threadIdx.x;
  if(t < CDIM) counts[t] = 0;
  if(t == 0){ enc[0] = 0xFFFFFFFFu; enc[1] = 0u; }
}

// ---------------- column mean, stage 1 (deterministic two-stage) ----------------
__global__ __launch_bounds__(256) void k_colmean1(const float* __restrict__ X, float* __restrict__ pbuf){
  int col = blockIdx.x * 256 + threadIdx.x;   // grid.x = 3
  int chunk = blockIdx.y;                     // 256 chunks
  int n0 = chunk * 86; int n1 = n0 + 86; if(n1 > NTOT) n1 = NTOT;
  float s = 0.f;
  for(int n = n0; n < n1; ++n) s += X[(size_t)n * DIM + col];
  pbuf[chunk * DIM + col] = s;
}

__global__ __launch_bounds__(768) void k_meanfin(const float* __restrict__ pbuf, float* __restrict__ meanv,
                                                 float* __restrict__ vvec, float* __restrict__ scal){
  __shared__ float sh[1024];
  int t = threadIdx.x;
  float s = 0.f;
  for(int c = 0; c < 256; ++c) s += pbuf[c * DIM + t];
  float m = s / 21904.0f;
  meanv[t] = m;
  float v0 = 1.0f / sqrtf(768.0f);
  vvec[t] = v0;
  sh[t] = m * v0; if(t < 256) sh[768 + t] = 0.f; __syncthreads();
  for(int st = 512; st > 0; st >>= 1){ if(t < st) sh[t] += sh[t+st]; __syncthreads(); }
  if(t == 0) scal[0] = sh[0];  // mv = dot(mean, v)
}

// ---------------- fused power-iteration pass: vraw = Xc^T (Xc v) ----------------
__global__ __launch_bounds__(256) void k_pcapass(const float* __restrict__ X,
    const float* __restrict__ vvec, const float* __restrict__ scal,
    float* __restrict__ pbuf, float* __restrict__ subuf){
  __shared__ float shacc[4][DIM];
  __shared__ float shsu[4];
  int t = threadIdx.x, w = t >> 6, l = t & 63;
  float mv = scal[0];
  const float4* v4 = (const float4*)(vvec + l * 12);
  float4 v0 = v4[0], v1 = v4[1], v2 = v4[2];
  float4 a0 = {0,0,0,0}, a1 = {0,0,0,0}, a2 = {0,0,0,0};
  float su = 0.f;
  for(int n = blockIdx.x * 4 + w; n < NTOT; n += 2048){
    const float4* x4 = (const float4*)(X + (size_t)n * DIM + l * 12);
    float4 x0 = x4[0], x1 = x4[1], x2 = x4[2];
    float tp = x0.x*v0.x + x0.y*v0.y + x0.z*v0.z + x0.w*v0.w
             + x1.x*v1.x + x1.y*v1.y + x1.z*v1.z + x1.w*v1.w
             + x2.x*v2.x + x2.y*v2.y + x2.z*v2.z + x2.w*v2.w;
    #pragma unroll
    for(int o = 32; o > 0; o >>= 1) tp += __shfl_xor(tp, o);
    tp -= mv;
    a0.x += tp*x0.x; a0.y += tp*x0.y; a0.z += tp*x0.z; a0.w += tp*x0.w;
    a1.x += tp*x1.x; a1.y += tp*x1.y; a1.z += tp*x1.z; a1.w += tp*x1.w;
    a2.x += tp*x2.x; a2.y += tp*x2.y; a2.z += tp*x2.z; a2.w += tp*x2.w;
    if(l == 0) su += tp;
  }
  float4* sh4 = (float4*)&shacc[w][l * 12];
  sh4[0] = a0; sh4[1] = a1; sh4[2] = a2;
  if(l == 0) shsu[w] = su;
  __syncthreads();
  for(int c = t; c < DIM; c += 256)
    pbuf[blockIdx.x * DIM + c] = shacc[0][c] + shacc[1][c] + shacc[2][c] + shacc[3][c];
  if(t == 0) subuf[blockIdx.x] = shsu[0] + shsu[1] + shsu[2] + shsu[3];
}

__global__ __launch_bounds__(768) void k_pcanorm(const float* __restrict__ pbuf,
    const float* __restrict__ subuf, const float* __restrict__ meanv,
    float* __restrict__ vvec, float* __restrict__ scal){
  __shared__ float sh[1024];
  int t = threadIdx.x;
  float sus = 0.f;
  if(t < 512) sus = subuf[t];
  sh[t] = sus;
  if(t < 256) sh[768 + t] = 0.f;
  __syncthreads();
  for(int st = 512; st > 0; st >>= 1){ if(t < st) sh[t] += sh[t+st]; __syncthreads(); }
  float su = sh[0]; __syncthreads();
  float s = 0.f;
  for(int b2 = 0; b2 < 512; ++b2) s += pbuf[b2 * DIM + t];
  float wv = s - meanv[t] * su;
  sh[t] = wv * wv; if(t < 256) sh[768 + t] = 0.f; __syncthreads();
  for(int st = 512; st > 0; st >>= 1){ if(t < st) sh[t] += sh[t+st]; __syncthreads(); }
  float nrm = sqrtf(sh[0]); __syncthreads();
  float nv = wv / (nrm + 1e-12f);
  vvec[t] = nv;
  sh[t] = meanv[t] * nv; if(t < 256) sh[768 + t] = 0.f; __syncthreads();
  for(int st = 512; st > 0; st >>= 1){ if(t < st) sh[t] += sh[t+st]; __syncthreads(); }
  if(t == 0) scal[0] = sh[0];  // mv for next pass
}

// ---------------- final u = Xc v, plus min/max ----------------
__global__ __launch_bounds__(256) void k_ufinal(const float* __restrict__ X,
    const float* __restrict__ vvec, const float* __restrict__ scal,
    float* __restrict__ u, unsigned* __restrict__ enc){
  __shared__ float smn[4], smx[4];
  int t = threadIdx.x, w = t >> 6, l = t & 63;
  float mv = scal[0];
  const float4* v4 = (const float4*)(vvec + l * 12);
  float4 v0 = v4[0], v1 = v4[1], v2 = v4[2];
  float lmn = 3.4e38f, lmx = -3.4e38f;
  for(int n = blockIdx.x * 4 + w; n < NTOT; n += 2048){
    const float4* x4 = (const float4*)(X + (size_t)n * DIM + l * 12);
    float4 x0 = x4[0], x1 = x4[1], x2 = x4[2];
    float tp = x0.x*v0.x + x0.y*v0.y + x0.z*v0.z + x0.w*v0.w
             + x1.x*v1.x + x1.y*v1.y + x1.z*v1.z + x1.w*v1.w
             + x2.x*v2.x + x2.y*v2.y + x2.z*v2.z + x2.w*v2.w;
    #pragma unroll
    for(int o = 32; o > 0; o >>= 1) tp += __shfl_xor(tp, o);
    tp -= mv;
    if(l == 0){ u[n] = tp; lmn = fminf(lmn, tp); lmx = fmaxf(lmx, tp); }
  }
  if(l == 0){ smn[w] = lmn; smx[w] = lmx; }
  __syncthreads();
  if(t == 0){
    float mn = fminf(fminf(smn[0], smn[1]), fminf(smn[2], smn[3]));
    float mx = fmaxf(fmaxf(smx[0], smx[1]), fmaxf(smx[2], smx[3]));
    atomicMin(&enc[0], encf(mn));
    atomicMax(&enc[1], encf(mx));
  }
}

// ---------------- pseudo labels ----------------
__global__ __launch_bounds__(256) void k_pseudo(const float* __restrict__ u,
    const unsigned* __restrict__ enc, const int* __restrict__ labels,
    int* __restrict__ pl, float* __restrict__ pseudo_out,
    float* __restrict__ assign_out, int* __restrict__ counts){
  int n = blockIdx.x * 256 + threadIdx.x;
  if(n >= NTOT) return;
  float mn = decf(enc[0]), mx = decf(enc[1]);
  float us = (u[n] - mn) / (mx - mn);
  int b = n / NPATCH;
  int p = (us <= 0.5f) ? labels[b] : NCLS;
  pl[n] = p;
  pseudo_out[n] = (float)p;
  assign_out[n] = -1.0f;
  atomicAdd(&counts[p], 1);
}

__global__ void k_rank(const int* __restrict__ counts, int* __restrict__ rankv){
  if(threadIdx.x == 0){
    int r = 0;
    for(int c = 0; c < NCLS; ++c){
      if(counts[c] > 0){ rankv[c] = r; r++; } else rankv[c] = 0;
    }
  }
}

// ---------------- row norms ----------------
__global__ __launch_bounds__(256) void k_rnorm(const float* __restrict__ X, float* __restrict__ rinv){
  int t = threadIdx.x, w = t >> 6, l = t & 63;
  int n = blockIdx.x * 4 + w;
  if(n >= NTOT) return;
  const float4* x4 = (const float4*)(X + (size_t)n * DIM + l * 12);
  float4 x0 = x4[0], x1 = x4[1], x2 = x4[2];
  float s = x0.x*x0.x + x0.y*x0.y + x0.z*x0.z + x0.w*x0.w
          + x1.x*x1.x + x1.y*x1.y + x1.z*x1.z + x1.w*x1.w
          + x2.x*x2.x + x2.y*x2.y + x2.z*x2.z + x2.w*x2.w;
  #pragma unroll
  for(int o = 32; o > 0; o >>= 1) s += __shfl_xor(s, o);
  if(l == 0) rinv[n] = 1.0f / (sqrtf(s) + 1e-12f);
}

// ---------------- normalized prototypes + bias2 = b . protn ----------------
__global__ __launch_bounds__(256) void k_protn(const float* __restrict__ P,
    const float* __restrict__ bvec, float* __restrict__ protn, float* __restrict__ bias2){
  int t = threadIdx.x, w = t >> 6, l = t & 63;
  int r = blockIdx.x * 4 + w;
  if(r >= NCK) return;
  const float4* x4 = (const float4*)(P + (size_t)r * DIM + l * 12);
  float4 x0 = x4[0], x1 = x4[1], x2 = x4[2];
  float s = x0.x*x0.x + x0.y*x0.y + x0.z*x0.z + x0.w*x0.w
          + x1.x*x1.x + x1.y*x1.y + x1.z*x1.z + x1.w*x1.w
          + x2.x*x2.x + x2.y*x2.y + x2.z*x2.z + x2.w*x2.w;
  #pragma unroll
  for(int o = 32; o > 0; o >>= 1) s += __shfl_xor(s, o);
  float rv = 1.0f / (sqrtf(s) + 1e-12f);
  x0.x *= rv; x0.y *= rv; x0.z *= rv; x0.w *= rv;
  x1.x *= rv; x1.y *= rv; x1.z *= rv; x1.w *= rv;
  x2.x *= rv; x2.y *= rv; x2.z *= rv; x2.w *= rv;
  float4* o4 = (float4*)(protn + (size_t)r * DIM + l * 12);
  o4[0] = x0; o4[1] = x1; o4[2] = x2;
  const float4* b4 = (const float4*)(bvec + l * 12);
  float4 b0 = b4[0], b1 = b4[1], b2 = b4[2];
  float bb = b0.x*x0.x + b0.y*x0.y + b0.z*x0.z + b0.w*x0.w
           + b1.x*x1.x + b1.y*x1.y + b1.z*x1.z + b1.w*x1.w
           + b2.x*x2.x + b2.y*x2.y + b2.z*x2.z + b2.w*x2.w;
  #pragma unroll
  for(int o = 32; o > 0; o >>= 1) bb += __shfl_xor(bb, o);
  if(l == 0) bias2[r] = bb;
}

// ---------------- NT GEMM: C[M,N] = A[M,K] * B[N,K]^T (+ scale/bias/add) ----------------
template<int HAS_SCALE, int HAS_BIAS, int HAS_ADD>
__global__ __launch_bounds__(256) void k_gemm_nt(const float* __restrict__ A,
    const float* __restrict__ B, float* __restrict__ C,
    const float* __restrict__ rowScale, const float* __restrict__ colBias,
    const float* __restrict__ addMat, int M, int N, int K){
  __shared__ float As[32][72];
  __shared__ float Bs[32][72];
  int t = threadIdx.x;
  int m0 = blockIdx.y * 64, n0 = blockIdx.x * 64;
  int srow = t >> 2, skq = (t & 3) * 8;
  int ty = t >> 4, tx = t & 15;
  int i0 = ty * 4, j0 = tx * 4;
  float acc[4][4] = {};
  int gra = m0 + srow; bool va = gra < M;
  int grb = n0 + srow; bool vb = grb < N;
  float scale = 1.0f;
  if(HAS_SCALE && va) scale = rowScale[gra];
  const float* Aptr = A + (size_t)gra * K + skq;
  const float* Bptr = B + (size_t)grb * K + skq;
  for(int k0 = 0; k0 < K; k0 += 32){
    float4 a0 = {0,0,0,0}, a1 = {0,0,0,0}, b0 = {0,0,0,0}, b1 = {0,0,0,0};
    if(va){ a0 = *(const float4*)(Aptr + k0); a1 = *(const float4*)(Aptr + k0 + 4); }
    if(vb){ b0 = *(const float4*)(Bptr + k0); b1 = *(const float4*)(Bptr + k0 + 4); }
    if(HAS_SCALE){
      a0.x *= scale; a0.y *= scale; a0.z *= scale; a0.w *= scale;
      a1.x *= scale; a1.y *= scale; a1.z *= scale; a1.w *= scale;
    }
    __syncthreads();
    As[skq+0][srow] = a0.x; As[skq+1][srow] = a0.y; As[skq+2][srow] = a0.z; As[skq+3][srow] = a0.w;
    As[skq+4][srow] = a1.x; As[skq+5][srow] = a1.y; As[skq+6][srow] = a1.z; As[skq+7][srow] = a1.w;
    Bs[skq+0][srow] = b0.x; Bs[skq+1][srow] = b0.y; Bs[skq+2][srow] = b0.z; Bs[skq+3][srow] = b0.w;
    Bs[skq+4][srow] = b1.x; Bs[skq+5][srow] = b1.y; Bs[skq+6][srow] = b1.z; Bs[skq+7][srow] = b1.w;
    __syncthreads();
    #pragma unroll
    for(int kk = 0; kk < 32; ++kk){
      float4 avv = *(const float4*)&As[kk][i0];
      float4 bvv = *(const float4*)&Bs[kk][j0];
      float a_[4] = {avv.x, avv.y, avv.z, avv.w};
      float b_[4] = {bvv.x, bvv.y, bvv.z, bvv.w};
      #pragma unroll
      for(int i = 0; i < 4; ++i)
        #pragma unroll
        for(int j = 0; j < 4; ++j)
          acc[i][j] += a_[i] * b_[j];
    }
  }
  #pragma unroll
  for(int i = 0; i < 4; ++i){
    int gr = m0 + i0 + i; if(gr >= M) continue;
    #pragma unroll
    for(int j = 0; j < 4; ++j){
      int gc = n0 + j0 + j; if(gc >= N) continue;
      float v2 = acc[i][j];
      if(HAS_BIAS) v2 += colBias[gc];
      if(HAS_ADD) v2 += addMat[(size_t)gr * N + gc];
      C[(size_t)gr * N + gc] = v2;
    }
  }
}

// ---------------- per-class masked Sinkhorn ----------------
__global__ __launch_bounds__(256) void k_sinkhorn(const float* __restrict__ logits,
    const int* __restrict__ pl, const int* __restrict__ counts, const int* __restrict__ rankv,
    const int* __restrict__ labels, float* __restrict__ Aw, float* __restrict__ assign_out){
  int c = blockIdx.x;
  int NcI = counts[c];
  if(NcI == 0) return;
  __shared__ int imgs[BIMG];
  __shared__ int nimgS;
  __shared__ float sh[256];
  int t = threadIdx.x;
  if(t == 0){
    int ni = 0;
    for(int b = 0; b < BIMG; ++b) if(labels[b] == c) imgs[ni++] = b;
    nimgS = ni;
  }
  __syncthreads();
  int tot = nimgS * NPATCH;
  float Ncf = (float)NcI;
  float invNc = 1.0f / Ncf;

  // phase 0: exp + total sum
  float sp = 0.f;
  for(int ii = t; ii < tot; ii += 256){
    int n = imgs[ii / NPATCH] * NPATCH + (ii % NPATCH);
    if(pl[n] != c) continue;
    const float* lg = logits + (size_t)n * NCK + c * KP;
    float* aw = Aw + (size_t)n * KP;
    float l0 = expf(lg[0] / 0.05f), l1 = expf(lg[1] / 0.05f), l2 = expf(lg[2] / 0.05f),
          l3 = expf(lg[3] / 0.05f), l4 = expf(lg[4] / 0.05f);
    aw[0] = l0; aw[1] = l1; aw[2] = l2; aw[3] = l3; aw[4] = l4;
    sp += l0 + l1 + l2 + l3 + l4;
  }
  float S = red256(sp, sh);
  float sc = 1.0f / (S + 1e-16f);

  // scale + first column sums
  float cs0 = 0, cs1 = 0, cs2 = 0, cs3 = 0, cs4 = 0;
  for(int ii = t; ii < tot; ii += 256){
    int n = imgs[ii / NPATCH] * NPATCH + (ii % NPATCH);
    if(pl[n] != c) continue;
    float* aw = Aw + (size_t)n * KP;
    float l0 = aw[0]*sc, l1 = aw[1]*sc, l2 = aw[2]*sc, l3 = aw[3]*sc, l4 = aw[4]*sc;
    aw[0] = l0; aw[1] = l1; aw[2] = l2; aw[3] = l3; aw[4] = l4;
    cs0 += l0; cs1 += l1; cs2 += l2; cs3 += l3; cs4 += l4;
  }
  cs0 = red256(cs0, sh); cs1 = red256(cs1, sh); cs2 = red256(cs2, sh);
  cs3 = red256(cs3, sh); cs4 = red256(cs4, sh);

  for(int it = 0; it < 3; ++it){
    float m0 = 1.0f/(cs0+1e-16f), m1 = 1.0f/(cs1+1e-16f), m2 = 1.0f/(cs2+1e-16f),
          m3 = 1.0f/(cs3+1e-16f), m4 = 1.0f/(cs4+1e-16f);
    bool last = (it == 2);
    float n0 = 0, n1 = 0, n2 = 0, n3 = 0, n4 = 0;
    for(int ii = t; ii < tot; ii += 256){
      int n = imgs[ii / NPATCH] * NPATCH + (ii % NPATCH);
      if(pl[n] != c) continue;
      float* aw = Aw + (size_t)n * KP;
      float l0 = aw[0]*m0*0.2f, l1 = aw[1]*m1*0.2f, l2 = aw[2]*m2*0.2f,
            l3 = aw[3]*m3*0.2f, l4 = aw[4]*m4*0.2f;
      float rs = l0 + l1 + l2 + l3 + l4;
      float rw = 1.0f / (rs + 1e-16f);
      if(last){
        l0 *= rw; l1 *= rw; l2 *= rw; l3 *= rw; l4 *= rw;
        aw[0] = l0; aw[1] = l1; aw[2] = l2; aw[3] = l3; aw[4] = l4;
        int am = 0; float bv = l0;
        if(l1 > bv){ bv = l1; am = 1; }
        if(l2 > bv){ bv = l2; am = 2; }
        if(l3 > bv){ bv = l3; am = 3; }
        if(l4 > bv){ bv = l4; am = 4; }
        assign_out[n] = (float)(am + KP * rankv[c]);
      } else {
        float w2 = rw * invNc;
        l0 *= w2; l1 *= w2; l2 *= w2; l3 *= w2; l4 *= w2;
        aw[0] = l0; aw[1] = l1; aw[2] = l2; aw[3] = l3; aw[4] = l4;
        n0 += l0; n1 += l1; n2 += l2; n3 += l3; n4 += l4;
      }
    }
    if(!last){
      cs0 = red256(n0, sh); cs1 = red256(n1, sh); cs2 = red256(n2, sh);
      cs3 = red256(n3, sh); cs4 = red256(n4, sh);
    }
  }
}

// ---------------- P_new partial sums: part[b][ch][k][d] ----------------
__global__ __launch_bounds__(256) void k_pnew_part(const float* __restrict__ X,
    const float* __restrict__ rinv, const float* __restrict__ Aw,
    const int* __restrict__ pl, const int* __restrict__ labels,
    float* __restrict__ part){
  int b = blockIdx.y, ch = blockIdx.x;
  int c = labels[b];
  int t = threadIdx.x;
  int j0 = ch * 86, j1 = j0 + 86; if(j1 > NPATCH) j1 = NPATCH;
  float acc[3][5] = {};
  for(int j = j0; j < j1; ++j){
    int n = b * NPATCH + j;
    if(pl[n] != c) continue;
    const float* aw = Aw + (size_t)n * KP;
    float a0 = aw[0], a1 = aw[1], a2 = aw[2], a3 = aw[3], a4 = aw[4];
    float rv = rinv[n];
    #pragma unroll
    for(int dj = 0; dj < 3; ++dj){
      float x = X[(size_t)n * DIM + t + dj * 256] * rv;
      acc[dj][0] += a0 * x; acc[dj][1] += a1 * x; acc[dj][2] += a2 * x;
      acc[dj][3] += a3 * x; acc[dj][4] += a4 * x;
    }
  }
  float* po = part + ((size_t)(b * PCH + ch)) * KP * DIM;
  #pragma unroll
  for(int k = 0; k < 5; ++k)
    #pragma unroll
    for(int dj = 0; dj < 3; ++dj)
      po[k * DIM + t + dj * 256] = acc[dj][k];
}

// ---------------- P_new final: sum partials (fixed order) + EMA ----------------
__global__ __launch_bounds__(256) void k_pnew_fin(const float* __restrict__ P,
    const float* __restrict__ part, const int* __restrict__ counts,
    const int* __restrict__ labels, float* __restrict__ out_np){
  int c = blockIdx.x;
  int t = threadIdx.x;
  bool pres = (c < NCLS) && (counts[c] > 0);
  const float* Pc = P + (size_t)c * KP * DIM;
  float* Oc = out_np + (size_t)c * KP * DIM;
  if(!pres){
    for(int i = t; i < KP * DIM; i += 256) Oc[i] = Pc[i];
    return;
  }
  __shared__ int imgs[BIMG];
  __shared__ int nimgS;
  if(t == 0){
    int ni = 0;
    for(int b = 0; b < BIMG; ++b) if(labels[b] == c) imgs[ni++] = b;
    nimgS = ni;
  }
  __syncthreads();
  int ni = nimgS;
  for(int i = t; i < KP * DIM; i += 256){
    float s = 0.f;
    for(int q = 0; q < ni; ++q){
      const float* pb = part + ((size_t)(imgs[q] * PCH)) * KP * DIM + i;
      for(int ch = 0; ch < PCH; ++ch) s += pb[(size_t)ch * KP * DIM];
    }
    Oc[i] = 0.99f * Pc[i] + 0.01f * s;
  }
}

// ---------------- pooled stage 1: column sums per (image, chunk) ----------------
__global__ __launch_bounds__(256) void k_pool1(const float* __restrict__ logits,
    float* __restrict__ poolPart){
  int b = blockIdx.y, ch = blockIdx.x;
  int t = threadIdx.x;
  int j0 = ch * 43, j1 = j0 + 43; if(j1 > NPATCH) j1 = NPATCH;
  float a0 = 0, a1 = 0, a2 = 0, a3 = 0;
  for(int j = j0; j < j1; ++j){
    const float* row = logits + ((size_t)(b * NPATCH + j)) * NCK;
    a0 += row[t]; a1 += row[t + 256]; a2 += row[t + 512];
    if(t < 237) a3 += row[t + 768];
  }
  float* po = poolPart + ((size_t)(b * QCH + ch)) * 1024;
  po[t] = a0; po[t + 256] = a1; po[t + 512] = a2;
  if(t < 237) po[t + 768] = a3;
}

// ---------------- pooled stage 2 ----------------
__global__ __launch_bounds__(256) void k_pool2(const float* __restrict__ poolPart,
    float* __restrict__ pooled){
  int b = blockIdx.x;
  int t = threadIdx.x;
  float s0 = 0, s1 = 0, s2 = 0, s3 = 0;
  const float* pb = poolPart + ((size_t)(b * QCH)) * 1024;
  for(int ch = 0; ch < QCH; ++ch){
    const float* p = pb + (size_t)ch * 1024;
    s0 += p[t]; s1 += p[t + 256]; s2 += p[t + 512];
    if(t < 237) s3 += p[t + 768];
  }
  float* o = pooled + (size_t)b * NCK;
  o[t] = s0 / 1369.0f; o[t + 256] = s1 / 1369.0f; o[t + 512] = s2 / 1369.0f;
  if(t < 237) o[t + 768] = s3 / 1369.0f;
}

// ---------------- class logits (sa head) ----------------
__global__ __launch_bounds__(256) void k_cls(const float* __restrict__ pooled,
    const float* __restrict__ sa, float* __restrict__ out){
  int b = blockIdx.x;
  int i = threadIdx.x;
  if(i >= NCLS) return;
  float s0 = sa[i*5+0], s1 = sa[i*5+1], s2 = sa[i*5+2], s3 = sa[i*5+3], s4 = sa[i*5+4];
  float mx = fmaxf(fmaxf(fmaxf(s0, s1), fmaxf(s2, s3)), s4);
  float e0 = expf(s0 - mx), e1 = expf(s1 - mx), e2 = expf(s2 - mx),
        e3 = expf(s3 - mx), e4 = expf(s4 - mx);
  float se = e0 + e1 + e2 + e3 + e4;
  float iv = 5.0f / se;
  const float* p = pooled + (size_t)b * NCK + i * KP;
  float cl = p[0]*e0*iv + p[1]*e1*iv + p[2]*e2*iv + p[3]*e3*iv + p[4]*e4*iv;
  out[b * NCLS + i] = cl;
}

extern "C" void kernel_launch(void* const* d_in, const int* in_sizes, int n_in,
                              void* d_out, int out_size, void* d_ws, size_t ws_size,
                              hipStream_t stream){
  const float* X      = (const float*)d_in[0];   // patch_tokens [16,1369,768]
  const int*   labels = (const int*)d_in[1];     // [16]
  const float* P      = (const float*)d_in[2];   // prototypes [201,5,768]
  const float* W      = (const float*)d_in[3];   // [768,768]
  const float* bvec   = (const float*)d_in[4];   // [768]
  const float* sa     = (const float*)d_in[5];   // [200,5]

  float* out        = (float*)d_out;
  float* out_cls    = out;                                  // 3200
  float* out_logits = out + 3200;                           // 22013880
  float* out_pooled = out_logits + (size_t)NTOT * NCK;      // 16080
  float* out_assign = out_pooled + BIMG * NCK;              // 21904
  float* out_np     = out_assign + NTOT;                    // 771840
  float* out_pseudo = out_np + (size_t)CDIM * KP * DIM;     // 21904

  float* ws     = (float*)d_ws;
  float* protn  = ws;                                  // 1005*768
  float* Bmat   = protn + (size_t)NCK * DIM;           // 1005*768
  float* bias2  = Bmat + (size_t)NCK * DIM;            // 1024
  float* rinv   = bias2 + 1024;                        // 21904
  float* uvec   = rinv + NTOT;                         // 21904
  float* Aw     = uvec + NTOT;                         // 21904*5
  float* meanv  = Aw + (size_t)NTOT * KP;              // 768
  float* vvec   = meanv + DIM;                         // 768
  float* pbuf   = vvec + DIM;                          // 512*768
  float* subuf  = pbuf + 512 * DIM;                    // 512
  float* scal   = subuf + 512;                         // 8
  int*   pli    = (int*)(scal + 8);                    // 21904
  int*   counts = pli + NTOT;                          // 256
  int*   rankv  = counts + 256;                        // 256
  float* pnewP  = (float*)(rankv + 256);               // 16*16*5*768 = 983040
  float* poolP  = pnewP + (size_t)BIMG * PCH * KP * DIM;  // 16*32*1024 = 524288
  unsigned* enc = (unsigned*)(scal + 1);

  k_init<<<1, 256, 0, stream>>>(counts, enc);
  k_colmean1<<<dim3(3, 256), 256, 0, stream>>>(X, pbuf);
  k_meanfin<<<1, 768, 0, stream>>>(pbuf, meanv, vvec, scal);
  for(int i = 0; i < 10; ++i){
    k_pcapass<<<512, 256, 0, stream>>>(X, vvec, scal, pbuf, subuf);
    k_pcanorm<<<1, 768, 0, stream>>>(pbuf, subuf, meanv, vvec, scal);
  }
  k_ufinal<<<512, 256, 0, stream>>>(X, vvec, scal, uvec, enc);
  k_pseudo<<<86, 256, 0, stream>>>(uvec, enc, labels, pli, out_pseudo, out_assign, counts);
  k_rank<<<1, 64, 0, stream>>>(counts, rankv);
  k_rnorm<<<5476, 256, 0, stream>>>(X, rinv);
  k_protn<<<252, 256, 0, stream>>>(P, bvec, protn, bias2);
  // BmatT[r,e] = protn[r,e] + sum_d W[e,d]*protn[r,d]
  k_gemm_nt<0, 0, 1><<<dim3(12, 16), 256, 0, stream>>>(protn, W, Bmat, nullptr, nullptr, protn, NCK, DIM, DIM);
  // logits[n,ck] = sum_e ptn[n,e]*BmatT[ck,e] + bias2[ck]
  k_gemm_nt<1, 1, 0><<<dim3(16, 343), 256, 0, stream>>>(X, Bmat, out_logits, rinv, bias2, nullptr, NTOT, NCK, DIM);
  k_sinkhorn<<<NCLS, 256, 0, stream>>>(out_logits, pli, counts, rankv, labels, Aw, out_assign);
  k_pnew_part<<<dim3(PCH, BIMG), 256, 0, stream>>>(X, rinv, Aw, pli, labels, pnewP);
  k_pnew_fin<<<CDIM, 256, 0, stream>>>(P, pnewP, counts, labels, out_np);
  k_pool1<<<dim3(QCH, BIMG), 256, 0, stream>>>(out_logits, poolP);
  k_pool2<<<BIMG, 256, 0, stream>>>(poolP, out_pooled);
  k_cls<<<BIMG, 256, 0, stream>>>(out_pooled, sa, out_cls);
}

// Round 3
// 1014.928 us; speedup vs baseline: 1.8476x; 1.2009x over previous
//
#include <hip/hip_runtime.h>

#define NTOT 21904
#define NPATCH 1369
#define BIMG 16
#define DIM 768
#define NCLS 200
#define CDIM 201
#define KP 5
#define NCK 1005
#define PCH 16   // pnew patch chunks per image
#define QCH 32   // pool patch chunks per image

typedef short bf16x8 __attribute__((ext_vector_type(8)));
typedef float f32x4v __attribute__((ext_vector_type(4)));

__device__ __forceinline__ unsigned encf(float x){
  unsigned b = __float_as_uint(x);
  return (b & 0x80000000u) ? ~b : (b | 0x80000000u);
}
__device__ __forceinline__ float decf(unsigned e){
  return (e & 0x80000000u) ? __uint_as_float(e ^ 0x80000000u) : __uint_as_float(~e);
}
__device__ __forceinline__ unsigned short f2bf(float f){
  unsigned u = __float_as_uint(f);
  u += 0x7FFFu + ((u >> 16) & 1u);
  return (unsigned short)(u >> 16);
}
__device__ __forceinline__ float bf2f(unsigned short h){
  return __uint_as_float(((unsigned)h) << 16);
}

__device__ __forceinline__ float red256(float v, float* sh){
  int t = threadIdx.x;
  sh[t] = v; __syncthreads();
  for(int s = 128; s > 0; s >>= 1){ if(t < s) sh[t] += sh[t+s]; __syncthreads(); }
  float r = sh[0]; __syncthreads();
  return r;
}

// ---------------- init ----------------
__global__ void k_init(int* counts, unsigned* enc){
  int t = threadIdx.x;
  if(t < CDIM) counts[t] = 0;
  if(t == 0){ enc[0] = 0xFFFFFFFFu; enc[1] = 0u; }
}

// ---------------- column mean, stage 1 ----------------
__global__ __launch_bounds__(256) void k_colmean1(const float* __restrict__ X, float* __restrict__ pbuf){
  int col = blockIdx.x * 256 + threadIdx.x;
  int chunk = blockIdx.y;
  int n0 = chunk * 86; int n1 = n0 + 86; if(n1 > NTOT) n1 = NTOT;
  float s = 0.f;
  for(int n = n0; n < n1; ++n) s += X[(size_t)n * DIM + col];
  pbuf[chunk * DIM + col] = s;
}

__global__ __launch_bounds__(768) void k_meanfin(const float* __restrict__ pbuf, float* __restrict__ meanv,
                                                 float* __restrict__ vvec, float* __restrict__ scal){
  __shared__ float sh[1024];
  int t = threadIdx.x;
  float s = 0.f;
  for(int c = 0; c < 256; ++c) s += pbuf[c * DIM + t];
  float m = s / 21904.0f;
  meanv[t] = m;
  float v0 = 1.0f / sqrtf(768.0f);
  vvec[t] = v0;
  sh[t] = m * v0; if(t < 256) sh[768 + t] = 0.f; __syncthreads();
  for(int st = 512; st > 0; st >>= 1){ if(t < st) sh[t] += sh[t+st]; __syncthreads(); }
  if(t == 0) scal[0] = sh[0];
}

// ---------------- fused power-iteration pass ----------------
__global__ __launch_bounds__(256) void k_pcapass(const float* __restrict__ X,
    const float* __restrict__ vvec, const float* __restrict__ scal,
    float* __restrict__ pbuf, float* __restrict__ subuf){
  __shared__ float shacc[4][DIM];
  __shared__ float shsu[4];
  int t = threadIdx.x, w = t >> 6, l = t & 63;
  float mv = scal[0];
  const float4* v4 = (const float4*)(vvec + l * 12);
  float4 v0 = v4[0], v1 = v4[1], v2 = v4[2];
  float4 a0 = {0,0,0,0}, a1 = {0,0,0,0}, a2 = {0,0,0,0};
  float su = 0.f;
  for(int n = blockIdx.x * 4 + w; n < NTOT; n += 2048){
    const float4* x4 = (const float4*)(X + (size_t)n * DIM + l * 12);
    float4 x0 = x4[0], x1 = x4[1], x2 = x4[2];
    float tp = x0.x*v0.x + x0.y*v0.y + x0.z*v0.z + x0.w*v0.w
             + x1.x*v1.x + x1.y*v1.y + x1.z*v1.z + x1.w*v1.w
             + x2.x*v2.x + x2.y*v2.y + x2.z*v2.z + x2.w*v2.w;
    #pragma unroll
    for(int o = 32; o > 0; o >>= 1) tp += __shfl_xor(tp, o);
    tp -= mv;
    a0.x += tp*x0.x; a0.y += tp*x0.y; a0.z += tp*x0.z; a0.w += tp*x0.w;
    a1.x += tp*x1.x; a1.y += tp*x1.y; a1.z += tp*x1.z; a1.w += tp*x1.w;
    a2.x += tp*x2.x; a2.y += tp*x2.y; a2.z += tp*x2.z; a2.w += tp*x2.w;
    if(l == 0) su += tp;
  }
  float4* sh4 = (float4*)&shacc[w][l * 12];
  sh4[0] = a0; sh4[1] = a1; sh4[2] = a2;
  if(l == 0) shsu[w] = su;
  __syncthreads();
  for(int c = t; c < DIM; c += 256)
    pbuf[blockIdx.x * DIM + c] = shacc[0][c] + shacc[1][c] + shacc[2][c] + shacc[3][c];
  if(t == 0) subuf[blockIdx.x] = shsu[0] + shsu[1] + shsu[2] + shsu[3];
}

__global__ __launch_bounds__(768) void k_pcanorm(const float* __restrict__ pbuf,
    const float* __restrict__ subuf, const float* __restrict__ meanv,
    float* __restrict__ vvec, float* __restrict__ scal){
  __shared__ float sh[1024];
  int t = threadIdx.x;
  float sus = 0.f;
  if(t < 512) sus = subuf[t];
  sh[t] = sus;
  if(t < 256) sh[768 + t] = 0.f;
  __syncthreads();
  for(int st = 512; st > 0; st >>= 1){ if(t < st) sh[t] += sh[t+st]; __syncthreads(); }
  float su = sh[0]; __syncthreads();
  float s = 0.f;
  for(int b2 = 0; b2 < 512; ++b2) s += pbuf[b2 * DIM + t];
  float wv = s - meanv[t] * su;
  sh[t] = wv * wv; if(t < 256) sh[768 + t] = 0.f; __syncthreads();
  for(int st = 512; st > 0; st >>= 1){ if(t < st) sh[t] += sh[t+st]; __syncthreads(); }
  float nrm = sqrtf(sh[0]); __syncthreads();
  float nv = wv / (nrm + 1e-12f);
  vvec[t] = nv;
  sh[t] = meanv[t] * nv; if(t < 256) sh[768 + t] = 0.f; __syncthreads();
  for(int st = 512; st > 0; st >>= 1){ if(t < st) sh[t] += sh[t+st]; __syncthreads(); }
  if(t == 0) scal[0] = sh[0];
}

// ---------------- final u = Xc v, plus min/max ----------------
__global__ __launch_bounds__(256) void k_ufinal(const float* __restrict__ X,
    const float* __restrict__ vvec, const float* __restrict__ scal,
    float* __restrict__ u, unsigned* __restrict__ enc){
  __shared__ float smn[4], smx[4];
  int t = threadIdx.x, w = t >> 6, l = t & 63;
  float mv = scal[0];
  const float4* v4 = (const float4*)(vvec + l * 12);
  float4 v0 = v4[0], v1 = v4[1], v2 = v4[2];
  float lmn = 3.4e38f, lmx = -3.4e38f;
  for(int n = blockIdx.x * 4 + w; n < NTOT; n += 2048){
    const float4* x4 = (const float4*)(X + (size_t)n * DIM + l * 12);
    float4 x0 = x4[0], x1 = x4[1], x2 = x4[2];
    float tp = x0.x*v0.x + x0.y*v0.y + x0.z*v0.z + x0.w*v0.w
             + x1.x*v1.x + x1.y*v1.y + x1.z*v1.z + x1.w*v1.w
             + x2.x*v2.x + x2.y*v2.y + x2.z*v2.z + x2.w*v2.w;
    #pragma unroll
    for(int o = 32; o > 0; o >>= 1) tp += __shfl_xor(tp, o);
    tp -= mv;
    if(l == 0){ u[n] = tp; lmn = fminf(lmn, tp); lmx = fmaxf(lmx, tp); }
  }
  if(l == 0){ smn[w] = lmn; smx[w] = lmx; }
  __syncthreads();
  if(t == 0){
    float mn = fminf(fminf(smn[0], smn[1]), fminf(smn[2], smn[3]));
    float mx = fmaxf(fmaxf(smx[0], smx[1]), fmaxf(smx[2], smx[3]));
    atomicMin(&enc[0], encf(mn));
    atomicMax(&enc[1], encf(mx));
  }
}

// ---------------- pseudo labels ----------------
__global__ __launch_bounds__(256) void k_pseudo(const float* __restrict__ u,
    const unsigned* __restrict__ enc, const int* __restrict__ labels,
    int* __restrict__ pl, float* __restrict__ pseudo_out,
    float* __restrict__ assign_out, int* __restrict__ counts){
  int n = blockIdx.x * 256 + threadIdx.x;
  if(n >= NTOT) return;
  float mn = decf(enc[0]), mx = decf(enc[1]);
  float us = (u[n] - mn) / (mx - mn);
  int b = n / NPATCH;
  int p = (us <= 0.5f) ? labels[b] : NCLS;
  pl[n] = p;
  pseudo_out[n] = (float)p;
  assign_out[n] = -1.0f;
  atomicAdd(&counts[p], 1);
}

__global__ void k_rank(const int* __restrict__ counts, int* __restrict__ rankv){
  if(threadIdx.x == 0){
    int r = 0;
    for(int c = 0; c < NCLS; ++c){
      if(counts[c] > 0){ rankv[c] = r; r++; } else rankv[c] = 0;
    }
  }
}

// ---------------- row norms (fallback path) ----------------
__global__ __launch_bounds__(256) void k_rnorm(const float* __restrict__ X, float* __restrict__ rinv){
  int t = threadIdx.x, w = t >> 6, l = t & 63;
  int n = blockIdx.x * 4 + w;
  if(n >= NTOT) return;
  const float4* x4 = (const float4*)(X + (size_t)n * DIM + l * 12);
  float4 x0 = x4[0], x1 = x4[1], x2 = x4[2];
  float s = x0.x*x0.x + x0.y*x0.y + x0.z*x0.z + x0.w*x0.w
          + x1.x*x1.x + x1.y*x1.y + x1.z*x1.z + x1.w*x1.w
          + x2.x*x2.x + x2.y*x2.y + x2.z*x2.z + x2.w*x2.w;
  #pragma unroll
  for(int o = 32; o > 0; o >>= 1) s += __shfl_xor(s, o);
  if(l == 0) rinv[n] = 1.0f / (sqrtf(s) + 1e-12f);
}

// ---------------- row norm + bf16 hi/lo split of ptn = X*rinv ----------------
__global__ __launch_bounds__(256) void k_prep_a(const float* __restrict__ X,
    float* __restrict__ rinv, unsigned short* __restrict__ Ahi, unsigned short* __restrict__ Alo){
  int t = threadIdx.x, w = t >> 6, l = t & 63;
  int n = blockIdx.x * 4 + w;
  if(n >= NTOT) return;
  const float4* x4 = (const float4*)(X + (size_t)n * DIM + l * 12);
  float4 x0 = x4[0], x1 = x4[1], x2 = x4[2];
  float s = x0.x*x0.x + x0.y*x0.y + x0.z*x0.z + x0.w*x0.w
          + x1.x*x1.x + x1.y*x1.y + x1.z*x1.z + x1.w*x1.w
          + x2.x*x2.x + x2.y*x2.y + x2.z*x2.z + x2.w*x2.w;
  #pragma unroll
  for(int o = 32; o > 0; o >>= 1) s += __shfl_xor(s, o);
  float rv = 1.0f / (sqrtf(s) + 1e-12f);
  if(l == 0) rinv[n] = rv;
  float xs[12] = {x0.x*rv, x0.y*rv, x0.z*rv, x0.w*rv,
                  x1.x*rv, x1.y*rv, x1.z*rv, x1.w*rv,
                  x2.x*rv, x2.y*rv, x2.z*rv, x2.w*rv};
  unsigned short hi[12], lo[12];
  #pragma unroll
  for(int j = 0; j < 12; ++j){
    hi[j] = f2bf(xs[j]);
    lo[j] = f2bf(xs[j] - bf2f(hi[j]));
  }
  size_t off = (size_t)n * DIM + l * 12;
  #pragma unroll
  for(int j = 0; j < 3; ++j){
    *(ushort4*)(Ahi + off + j * 4) = make_ushort4(hi[j*4], hi[j*4+1], hi[j*4+2], hi[j*4+3]);
    *(ushort4*)(Alo + off + j * 4) = make_ushort4(lo[j*4], lo[j*4+1], lo[j*4+2], lo[j*4+3]);
  }
}

// ---------------- bf16 hi/lo split of Bmat (padded to 1024 rows) ----------------
__global__ __launch_bounds__(256) void k_prep_b(const float* __restrict__ Bmat,
    unsigned short* __restrict__ Bhi, unsigned short* __restrict__ Blo){
  int t = threadIdx.x, w = t >> 6, l = t & 63;
  int r = blockIdx.x * 4 + w;
  if(r >= 1024) return;
  size_t off = (size_t)r * DIM + l * 12;
  unsigned short hi[12], lo[12];
  if(r < NCK){
    const float4* x4 = (const float4*)(Bmat + off);
    float4 x0 = x4[0], x1 = x4[1], x2 = x4[2];
    float xs[12] = {x0.x, x0.y, x0.z, x0.w, x1.x, x1.y, x1.z, x1.w, x2.x, x2.y, x2.z, x2.w};
    #pragma unroll
    for(int j = 0; j < 12; ++j){
      hi[j] = f2bf(xs[j]);
      lo[j] = f2bf(xs[j] - bf2f(hi[j]));
    }
  } else {
    #pragma unroll
    for(int j = 0; j < 12; ++j){ hi[j] = 0; lo[j] = 0; }
  }
  #pragma unroll
  for(int j = 0; j < 3; ++j){
    *(ushort4*)(Bhi + off + j * 4) = make_ushort4(hi[j*4], hi[j*4+1], hi[j*4+2], hi[j*4+3]);
    *(ushort4*)(Blo + off + j * 4) = make_ushort4(lo[j*4], lo[j*4+1], lo[j*4+2], lo[j*4+3]);
  }
}

// ---------------- normalized prototypes + bias2 ----------------
__global__ __launch_bounds__(256) void k_protn(const float* __restrict__ P,
    const float* __restrict__ bvec, float* __restrict__ protn, float* __restrict__ bias2){
  int t = threadIdx.x, w = t >> 6, l = t & 63;
  int r = blockIdx.x * 4 + w;
  if(r >= NCK) return;
  const float4* x4 = (const float4*)(P + (size_t)r * DIM + l * 12);
  float4 x0 = x4[0], x1 = x4[1], x2 = x4[2];
  float s = x0.x*x0.x + x0.y*x0.y + x0.z*x0.z + x0.w*x0.w
          + x1.x*x1.x + x1.y*x1.y + x1.z*x1.z + x1.w*x1.w
          + x2.x*x2.x + x2.y*x2.y + x2.z*x2.z + x2.w*x2.w;
  #pragma unroll
  for(int o = 32; o > 0; o >>= 1) s += __shfl_xor(s, o);
  float rv = 1.0f / (sqrtf(s) + 1e-12f);
  x0.x *= rv; x0.y *= rv; x0.z *= rv; x0.w *= rv;
  x1.x *= rv; x1.y *= rv; x1.z *= rv; x1.w *= rv;
  x2.x *= rv; x2.y *= rv; x2.z *= rv; x2.w *= rv;
  float4* o4 = (float4*)(protn + (size_t)r * DIM + l * 12);
  o4[0] = x0; o4[1] = x1; o4[2] = x2;
  const float4* b4 = (const float4*)(bvec + l * 12);
  float4 b0 = b4[0], b1 = b4[1], b2 = b4[2];
  float bb = b0.x*x0.x + b0.y*x0.y + b0.z*x0.z + b0.w*x0.w
           + b1.x*x1.x + b1.y*x1.y + b1.z*x1.z + b1.w*x1.w
           + b2.x*x2.x + b2.y*x2.y + b2.z*x2.z + b2.w*x2.w;
  #pragma unroll
  for(int o = 32; o > 0; o >>= 1) bb += __shfl_xor(bb, o);
  if(l == 0) bias2[r] = bb;
}

// ---------------- f32 NT GEMM (small Bmat compute + fallback) ----------------
template<int HAS_SCALE, int HAS_BIAS, int HAS_ADD>
__global__ __launch_bounds__(256) void k_gemm_nt(const float* __restrict__ A,
    const float* __restrict__ B, float* __restrict__ C,
    const float* __restrict__ rowScale, const float* __restrict__ colBias,
    const float* __restrict__ addMat, int M, int N, int K){
  __shared__ float As[32][72];
  __shared__ float Bs[32][72];
  int t = threadIdx.x;
  int m0 = blockIdx.y * 64, n0 = blockIdx.x * 64;
  int srow = t >> 2, skq = (t & 3) * 8;
  int ty = t >> 4, tx = t & 15;
  int i0 = ty * 4, j0 = tx * 4;
  float acc[4][4] = {};
  int gra = m0 + srow; bool va = gra < M;
  int grb = n0 + srow; bool vb = grb < N;
  float scale = 1.0f;
  if(HAS_SCALE && va) scale = rowScale[gra];
  const float* Aptr = A + (size_t)gra * K + skq;
  const float* Bptr = B + (size_t)grb * K + skq;
  for(int k0 = 0; k0 < K; k0 += 32){
    float4 a0 = {0,0,0,0}, a1 = {0,0,0,0}, b0 = {0,0,0,0}, b1 = {0,0,0,0};
    if(va){ a0 = *(const float4*)(Aptr + k0); a1 = *(const float4*)(Aptr + k0 + 4); }
    if(vb){ b0 = *(const float4*)(Bptr + k0); b1 = *(const float4*)(Bptr + k0 + 4); }
    if(HAS_SCALE){
      a0.x *= scale; a0.y *= scale; a0.z *= scale; a0.w *= scale;
      a1.x *= scale; a1.y *= scale; a1.z *= scale; a1.w *= scale;
    }
    __syncthreads();
    As[skq+0][srow] = a0.x; As[skq+1][srow] = a0.y; As[skq+2][srow] = a0.z; As[skq+3][srow] = a0.w;
    As[skq+4][srow] = a1.x; As[skq+5][srow] = a1.y; As[skq+6][srow] = a1.z; As[skq+7][srow] = a1.w;
    Bs[skq+0][srow] = b0.x; Bs[skq+1][srow] = b0.y; Bs[skq+2][srow] = b0.z; Bs[skq+3][srow] = b0.w;
    Bs[skq+4][srow] = b1.x; Bs[skq+5][srow] = b1.y; Bs[skq+6][srow] = b1.z; Bs[skq+7][srow] = b1.w;
    __syncthreads();
    #pragma unroll
    for(int kk = 0; kk < 32; ++kk){
      float4 avv = *(const float4*)&As[kk][i0];
      float4 bvv = *(const float4*)&Bs[kk][j0];
      float a_[4] = {avv.x, avv.y, avv.z, avv.w};
      float b_[4] = {bvv.x, bvv.y, bvv.z, bvv.w};
      #pragma unroll
      for(int i = 0; i < 4; ++i)
        #pragma unroll
        for(int j = 0; j < 4; ++j)
          acc[i][j] += a_[i] * b_[j];
    }
  }
  #pragma unroll
  for(int i = 0; i < 4; ++i){
    int gr = m0 + i0 + i; if(gr >= M) continue;
    #pragma unroll
    for(int j = 0; j < 4; ++j){
      int gc = n0 + j0 + j; if(gc >= N) continue;
      float v2 = acc[i][j];
      if(HAS_BIAS) v2 += colBias[gc];
      if(HAS_ADD) v2 += addMat[(size_t)gr * N + gc];
      C[(size_t)gr * N + gc] = v2;
    }
  }
}

// ---------------- MFMA split-bf16 main GEMM: C = An * B^T + bias2 ----------------
__global__ __launch_bounds__(256) void k_gemm_mfma(
    const unsigned short* __restrict__ Ahi, const unsigned short* __restrict__ Alo,
    const unsigned short* __restrict__ Bhi, const unsigned short* __restrict__ Blo,
    const float* __restrict__ bias2, float* __restrict__ C){
  __shared__ unsigned short sA[2][4][128][8];   // [hi/lo][k-quad][row][8 bf16]
  __shared__ unsigned short sB[2][4][128][8];
  int h = blockIdx.x;
  int nt = h & 7, mt = h >> 3;           // n-strip per XCD (h%8), m streams
  int m0 = mt * 128, n0 = nt * 128;
  int t = threadIdx.x;
  int q = t >> 6, rr = t & 63;           // staging: k-quad, row-within-half
  int w = t >> 6, l = t & 63;
  int wm = w & 1, wn = w >> 1;           // wave -> 64x64 quadrant
  int lr = l & 15, lk = l >> 4;          // frag row/col, k-chunk
  f32x4v acc[4][4];
  #pragma unroll
  for(int i = 0; i < 4; ++i)
    #pragma unroll
    for(int j = 0; j < 4; ++j) acc[i][j] = (f32x4v){0.f, 0.f, 0.f, 0.f};

  for(int k0 = 0; k0 < DIM; k0 += 32){
    uint4 va0, va1, vl0, vl1, vb0, vb1, wb0, wb1;
    uint4 z; z.x = 0; z.y = 0; z.z = 0; z.w = 0;
    {
      int ra = m0 + rr;
      size_t offA = (size_t)ra * DIM + k0 + q * 8;
      va0 = (ra < NTOT) ? *(const uint4*)(Ahi + offA) : z;
      vl0 = (ra < NTOT) ? *(const uint4*)(Alo + offA) : z;
      int ra2 = ra + 64;
      size_t offA2 = (size_t)ra2 * DIM + k0 + q * 8;
      va1 = (ra2 < NTOT) ? *(const uint4*)(Ahi + offA2) : z;
      vl1 = (ra2 < NTOT) ? *(const uint4*)(Alo + offA2) : z;
      size_t offB = (size_t)(n0 + rr) * DIM + k0 + q * 8;
      vb0 = *(const uint4*)(Bhi + offB);
      wb0 = *(const uint4*)(Blo + offB);
      size_t offB2 = offB + (size_t)64 * DIM;
      vb1 = *(const uint4*)(Bhi + offB2);
      wb1 = *(const uint4*)(Blo + offB2);
    }
    __syncthreads();
    *(uint4*)&sA[0][q][rr][0]      = va0;
    *(uint4*)&sA[0][q][rr + 64][0] = va1;
    *(uint4*)&sA[1][q][rr][0]      = vl0;
    *(uint4*)&sA[1][q][rr + 64][0] = vl1;
    *(uint4*)&sB[0][q][rr][0]      = vb0;
    *(uint4*)&sB[0][q][rr + 64][0] = vb1;
    *(uint4*)&sB[1][q][rr][0]      = wb0;
    *(uint4*)&sB[1][q][rr + 64][0] = wb1;
    __syncthreads();
    bf16x8 ah[4], al[4], bh[4], bl[4];
    #pragma unroll
    for(int f = 0; f < 4; ++f){
      int ar = wm * 64 + f * 16 + lr;
      ah[f] = *(const bf16x8*)&sA[0][lk][ar][0];
      al[f] = *(const bf16x8*)&sA[1][lk][ar][0];
      int bc = wn * 64 + f * 16 + lr;
      bh[f] = *(const bf16x8*)&sB[0][lk][bc][0];
      bl[f] = *(const bf16x8*)&sB[1][lk][bc][0];
    }
    #pragma unroll
    for(int i = 0; i < 4; ++i)
      #pragma unroll
      for(int j = 0; j < 4; ++j){
        acc[i][j] = __builtin_amdgcn_mfma_f32_16x16x32_bf16(ah[i], bh[j], acc[i][j], 0, 0, 0);
        acc[i][j] = __builtin_amdgcn_mfma_f32_16x16x32_bf16(ah[i], bl[j], acc[i][j], 0, 0, 0);
        acc[i][j] = __builtin_amdgcn_mfma_f32_16x16x32_bf16(al[i], bh[j], acc[i][j], 0, 0, 0);
      }
  }
  #pragma unroll
  for(int i = 0; i < 4; ++i){
    #pragma unroll
    for(int j = 0; j < 4; ++j){
      int col = n0 + wn * 64 + j * 16 + lr;
      if(col >= NCK) continue;
      float bv = bias2[col];
      #pragma unroll
      for(int r2 = 0; r2 < 4; ++r2){
        int row = m0 + wm * 64 + i * 16 + lk * 4 + r2;
        if(row < NTOT) C[(size_t)row * NCK + col] = acc[i][j][r2] + bv;
      }
    }
  }
}

// ---------------- per-class masked Sinkhorn ----------------
__global__ __launch_bounds__(256) void k_sinkhorn(const float* __restrict__ logits,
    const int* __restrict__ pl, const int* __restrict__ counts, const int* __restrict__ rankv,
    const int* __restrict__ labels, float* __restrict__ Aw, float* __restrict__ assign_out){
  int c = blockIdx.x;
  int NcI = counts[c];
  if(NcI == 0) return;
  __shared__ int imgs[BIMG];
  __shared__ int nimgS;
  __shared__ float sh[256];
  int t = threadIdx.x;
  if(t == 0){
    int ni = 0;
    for(int b = 0; b < BIMG; ++b) if(labels[b] == c) imgs[ni++] = b;
    nimgS = ni;
  }
  __syncthreads();
  int tot = nimgS * NPATCH;
  float Ncf = (float)NcI;
  float invNc = 1.0f / Ncf;

  float sp = 0.f;
  for(int ii = t; ii < tot; ii += 256){
    int n = imgs[ii / NPATCH] * NPATCH + (ii % NPATCH);
    if(pl[n] != c) continue;
    const float* lg = logits + (size_t)n * NCK + c * KP;
    float* aw = Aw + (size_t)n * KP;
    float l0 = expf(lg[0] / 0.05f), l1 = expf(lg[1] / 0.05f), l2 = expf(lg[2] / 0.05f),
          l3 = expf(lg[3] / 0.05f), l4 = expf(lg[4] / 0.05f);
    aw[0] = l0; aw[1] = l1; aw[2] = l2; aw[3] = l3; aw[4] = l4;
    sp += l0 + l1 + l2 + l3 + l4;
  }
  float S = red256(sp, sh);
  float sc = 1.0f / (S + 1e-16f);

  float cs0 = 0, cs1 = 0, cs2 = 0, cs3 = 0, cs4 = 0;
  for(int ii = t; ii < tot; ii += 256){
    int n = imgs[ii / NPATCH] * NPATCH + (ii % NPATCH);
    if(pl[n] != c) continue;
    float* aw = Aw + (size_t)n * KP;
    float l0 = aw[0]*sc, l1 = aw[1]*sc, l2 = aw[2]*sc, l3 = aw[3]*sc, l4 = aw[4]*sc;
    aw[0] = l0; aw[1] = l1; aw[2] = l2; aw[3] = l3; aw[4] = l4;
    cs0 += l0; cs1 += l1; cs2 += l2; cs3 += l3; cs4 += l4;
  }
  cs0 = red256(cs0, sh); cs1 = red256(cs1, sh); cs2 = red256(cs2, sh);
  cs3 = red256(cs3, sh); cs4 = red256(cs4, sh);

  for(int it = 0; it < 3; ++it){
    float m0 = 1.0f/(cs0+1e-16f), m1 = 1.0f/(cs1+1e-16f), m2 = 1.0f/(cs2+1e-16f),
          m3 = 1.0f/(cs3+1e-16f), m4 = 1.0f/(cs4+1e-16f);
    bool last = (it == 2);
    float n0 = 0, n1 = 0, n2 = 0, n3 = 0, n4 = 0;
    for(int ii = t; ii < tot; ii += 256){
      int n = imgs[ii / NPATCH] * NPATCH + (ii % NPATCH);
      if(pl[n] != c) continue;
      float* aw = Aw + (size_t)n * KP;
      float l0 = aw[0]*m0*0.2f, l1 = aw[1]*m1*0.2f, l2 = aw[2]*m2*0.2f,
            l3 = aw[3]*m3*0.2f, l4 = aw[4]*m4*0.2f;
      float rs = l0 + l1 + l2 + l3 + l4;
      float rw = 1.0f / (rs + 1e-16f);
      if(last){
        l0 *= rw; l1 *= rw; l2 *= rw; l3 *= rw; l4 *= rw;
        aw[0] = l0; aw[1] = l1; aw[2] = l2; aw[3] = l3; aw[4] = l4;
        int am = 0; float bv = l0;
        if(l1 > bv){ bv = l1; am = 1; }
        if(l2 > bv){ bv = l2; am = 2; }
        if(l3 > bv){ bv = l3; am = 3; }
        if(l4 > bv){ bv = l4; am = 4; }
        assign_out[n] = (float)(am + KP * rankv[c]);
      } else {
        float w2 = rw * invNc;
        l0 *= w2; l1 *= w2; l2 *= w2; l3 *= w2; l4 *= w2;
        aw[0] = l0; aw[1] = l1; aw[2] = l2; aw[3] = l3; aw[4] = l4;
        n0 += l0; n1 += l1; n2 += l2; n3 += l3; n4 += l4;
      }
    }
    if(!last){
      cs0 = red256(n0, sh); cs1 = red256(n1, sh); cs2 = red256(n2, sh);
      cs3 = red256(n3, sh); cs4 = red256(n4, sh);
    }
  }
}

// ---------------- P_new partial sums ----------------
__global__ __launch_bounds__(256) void k_pnew_part(const float* __restrict__ X,
    const float* __restrict__ rinv, const float* __restrict__ Aw,
    const int* __restrict__ pl, const int* __restrict__ labels,
    float* __restrict__ part){
  int b = blockIdx.y, ch = blockIdx.x;
  int c = labels[b];
  int t = threadIdx.x;
  int j0 = ch * 86, j1 = j0 + 86; if(j1 > NPATCH) j1 = NPATCH;
  float acc[3][5] = {};
  for(int j = j0; j < j1; ++j){
    int n = b * NPATCH + j;
    if(pl[n] != c) continue;
    const float* aw = Aw + (size_t)n * KP;
    float a0 = aw[0], a1 = aw[1], a2 = aw[2], a3 = aw[3], a4 = aw[4];
    float rv = rinv[n];
    #pragma unroll
    for(int dj = 0; dj < 3; ++dj){
      float x = X[(size_t)n * DIM + t + dj * 256] * rv;
      acc[dj][0] += a0 * x; acc[dj][1] += a1 * x; acc[dj][2] += a2 * x;
      acc[dj][3] += a3 * x; acc[dj][4] += a4 * x;
    }
  }
  float* po = part + ((size_t)(b * PCH + ch)) * KP * DIM;
  #pragma unroll
  for(int k = 0; k < 5; ++k)
    #pragma unroll
    for(int dj = 0; dj < 3; ++dj)
      po[k * DIM + t + dj * 256] = acc[dj][k];
}

// ---------------- P_new final ----------------
__global__ __launch_bounds__(256) void k_pnew_fin(const float* __restrict__ P,
    const float* __restrict__ part, const int* __restrict__ counts,
    const int* __restrict__ labels, float* __restrict__ out_np){
  int c = blockIdx.x;
  int t = threadIdx.x;
  bool pres = (c < NCLS) && (counts[c] > 0);
  const float* Pc = P + (size_t)c * KP * DIM;
  float* Oc = out_np + (size_t)c * KP * DIM;
  if(!pres){
    for(int i = t; i < KP * DIM; i += 256) Oc[i] = Pc[i];
    return;
  }
  __shared__ int imgs[BIMG];
  __shared__ int nimgS;
  if(t == 0){
    int ni = 0;
    for(int b = 0; b < BIMG; ++b) if(labels[b] == c) imgs[ni++] = b;
    nimgS = ni;
  }
  __syncthreads();
  int ni = nimgS;
  for(int i = t; i < KP * DIM; i += 256){
    float s = 0.f;
    for(int q = 0; q < ni; ++q){
      const float* pb = part + ((size_t)(imgs[q] * PCH)) * KP * DIM + i;
      for(int ch = 0; ch < PCH; ++ch) s += pb[(size_t)ch * KP * DIM];
    }
    Oc[i] = 0.99f * Pc[i] + 0.01f * s;
  }
}

// ---------------- pooled stage 1 ----------------
__global__ __launch_bounds__(256) void k_pool1(const float* __restrict__ logits,
    float* __restrict__ poolPart){
  int b = blockIdx.y, ch = blockIdx.x;
  int t = threadIdx.x;
  int j0 = ch * 43, j1 = j0 + 43; if(j1 > NPATCH) j1 = NPATCH;
  float a0 = 0, a1 = 0, a2 = 0, a3 = 0;
  for(int j = j0; j < j1; ++j){
    const float* row = logits + ((size_t)(b * NPATCH + j)) * NCK;
    a0 += row[t]; a1 += row[t + 256]; a2 += row[t + 512];
    if(t < 237) a3 += row[t + 768];
  }
  float* po = poolPart + ((size_t)(b * QCH + ch)) * 1024;
  po[t] = a0; po[t + 256] = a1; po[t + 512] = a2;
  if(t < 237) po[t + 768] = a3;
}

// ---------------- pooled stage 2 ----------------
__global__ __launch_bounds__(256) void k_pool2(const float* __restrict__ poolPart,
    float* __restrict__ pooled){
  int b = blockIdx.x;
  int t = threadIdx.x;
  float s0 = 0, s1 = 0, s2 = 0, s3 = 0;
  const float* pb = poolPart + ((size_t)(b * QCH)) * 1024;
  for(int ch = 0; ch < QCH; ++ch){
    const float* p = pb + (size_t)ch * 1024;
    s0 += p[t]; s1 += p[t + 256]; s2 += p[t + 512];
    if(t < 237) s3 += p[t + 768];
  }
  float* o = pooled + (size_t)b * NCK;
  o[t] = s0 / 1369.0f; o[t + 256] = s1 / 1369.0f; o[t + 512] = s2 / 1369.0f;
  if(t < 237) o[t + 768] = s3 / 1369.0f;
}

// ---------------- class logits (sa head) ----------------
__global__ __launch_bounds__(256) void k_cls(const float* __restrict__ pooled,
    const float* __restrict__ sa, float* __restrict__ out){
  int b = blockIdx.x;
  int i = threadIdx.x;
  if(i >= NCLS) return;
  float s0 = sa[i*5+0], s1 = sa[i*5+1], s2 = sa[i*5+2], s3 = sa[i*5+3], s4 = sa[i*5+4];
  float mx = fmaxf(fmaxf(fmaxf(s0, s1), fmaxf(s2, s3)), s4);
  float e0 = expf(s0 - mx), e1 = expf(s1 - mx), e2 = expf(s2 - mx),
        e3 = expf(s3 - mx), e4 = expf(s4 - mx);
  float se = e0 + e1 + e2 + e3 + e4;
  float iv = 5.0f / se;
  const float* p = pooled + (size_t)b * NCK + i * KP;
  float cl = p[0]*e0*iv + p[1]*e1*iv + p[2]*e2*iv + p[3]*e3*iv + p[4]*e4*iv;
  out[b * NCLS + i] = cl;
}

extern "C" void kernel_launch(void* const* d_in, const int* in_sizes, int n_in,
                              void* d_out, int out_size, void* d_ws, size_t ws_size,
                              hipStream_t stream){
  const float* X      = (const float*)d_in[0];
  const int*   labels = (const int*)d_in[1];
  const float* P      = (const float*)d_in[2];
  const float* W      = (const float*)d_in[3];
  const float* bvec   = (const float*)d_in[4];
  const float* sa     = (const float*)d_in[5];

  float* out        = (float*)d_out;
  float* out_cls    = out;
  float* out_logits = out + 3200;
  float* out_pooled = out_logits + (size_t)NTOT * NCK;
  float* out_assign = out_pooled + BIMG * NCK;
  float* out_np     = out_assign + NTOT;
  float* out_pseudo = out_np + (size_t)CDIM * KP * DIM;

  const size_t AHI_F = (size_t)NTOT * DIM / 2;   // ushort array in float units
  const size_t BHI_F = (size_t)1024 * DIM / 2;
  const size_t MFMA_F = 2 * AHI_F + 2 * BHI_F;   // 17,608,704 floats
  const size_t BASE_F = 3700000;                 // everything else (~14.5 MB), rounded up
  bool use_mfma = ws_size >= (MFMA_F + BASE_F) * sizeof(float);

  float* ws = (float*)d_ws;
  unsigned short* Ahi = (unsigned short*)ws;
  unsigned short* Alo = (unsigned short*)(ws + AHI_F);
  unsigned short* Bhi = (unsigned short*)(ws + 2 * AHI_F);
  unsigned short* Blo = (unsigned short*)(ws + 2 * AHI_F + BHI_F);
  float* base = use_mfma ? (ws + MFMA_F) : ws;

  float* protn  = base;
  float* Bmat   = protn + (size_t)NCK * DIM;
  float* bias2  = Bmat + (size_t)NCK * DIM;
  float* rinv   = bias2 + 1024;
  float* uvec   = rinv + NTOT;
  float* Aw     = uvec + NTOT;
  float* meanv  = Aw + (size_t)NTOT * KP;
  float* vvec   = meanv + DIM;
  float* pbuf   = vvec + DIM;
  float* subuf  = pbuf + 512 * DIM;
  float* scal   = subuf + 512;
  int*   pli    = (int*)(scal + 8);
  int*   counts = pli + NTOT;
  int*   rankv  = counts + 256;
  float* pnewP  = (float*)(rankv + 256);
  float* poolP  = pnewP + (size_t)BIMG * PCH * KP * DIM;
  unsigned* enc = (unsigned*)(scal + 1);

  k_init<<<1, 256, 0, stream>>>(counts, enc);
  k_colmean1<<<dim3(3, 256), 256, 0, stream>>>(X, pbuf);
  k_meanfin<<<1, 768, 0, stream>>>(pbuf, meanv, vvec, scal);
  for(int i = 0; i < 10; ++i){
    k_pcapass<<<512, 256, 0, stream>>>(X, vvec, scal, pbuf, subuf);
    k_pcanorm<<<1, 768, 0, stream>>>(pbuf, subuf, meanv, vvec, scal);
  }
  k_ufinal<<<512, 256, 0, stream>>>(X, vvec, scal, uvec, enc);
  k_pseudo<<<86, 256, 0, stream>>>(uvec, enc, labels, pli, out_pseudo, out_assign, counts);
  k_rank<<<1, 64, 0, stream>>>(counts, rankv);
  if(use_mfma){
    k_prep_a<<<5476, 256, 0, stream>>>(X, rinv, Ahi, Alo);
  } else {
    k_rnorm<<<5476, 256, 0, stream>>>(X, rinv);
  }
  k_protn<<<252, 256, 0, stream>>>(P, bvec, protn, bias2);
  k_gemm_nt<0, 0, 1><<<dim3(12, 16), 256, 0, stream>>>(protn, W, Bmat, nullptr, nullptr, protn, NCK, DIM, DIM);
  if(use_mfma){
    k_prep_b<<<256, 256, 0, stream>>>(Bmat, Bhi, Blo);
    k_gemm_mfma<<<1376, 256, 0, stream>>>(Ahi, Alo, Bhi, Blo, bias2, out_logits);
  } else {
    k_gemm_nt<1, 1, 0><<<dim3(16, 343), 256, 0, stream>>>(X, Bmat, out_logits, rinv, bias2, nullptr, NTOT, NCK, DIM);
  }
  k_sinkhorn<<<NCLS, 256, 0, stream>>>(out_logits, pli, counts, rankv, labels, Aw, out_assign);
  k_pnew_part<<<dim3(PCH, BIMG), 256, 0, stream>>>(X, rinv, Aw, pli, labels, pnewP);
  k_pnew_fin<<<CDIM, 256, 0, stream>>>(P, pnewP, counts, labels, out_np);
  k_pool1<<<dim3(QCH, BIMG), 256, 0, stream>>>(out_logits, poolP);
  k_pool2<<<BIMG, 256, 0, stream>>>(poolP, out_pooled);
  k_cls<<<BIMG, 256, 0, stream>>>(out_pooled, sa, out_cls);
}

// Round 4
// 822.104 us; speedup vs baseline: 2.2809x; 1.2345x over previous
//
#include <hip/hip_runtime.h>

#define NTOT 21904
#define MPAD 22016
#define NPATCH 1369
#define BIMG 16
#define DIM 768
#define NCLS 200
#define CDIM 201
#define KP 5
#define NCK 1005
#define PCH 16   // pnew patch chunks per image
#define QCH 32   // pool patch chunks per image

typedef short bf16x8 __attribute__((ext_vector_type(8)));
typedef float f32x4v __attribute__((ext_vector_type(4)));

__device__ __forceinline__ unsigned encf(float x){
  unsigned b = __float_as_uint(x);
  return (b & 0x80000000u) ? ~b : (b | 0x80000000u);
}
__device__ __forceinline__ float decf(unsigned e){
  return (e & 0x80000000u) ? __uint_as_float(e ^ 0x80000000u) : __uint_as_float(~e);
}
__device__ __forceinline__ unsigned short f2bf(float f){
  unsigned u = __float_as_uint(f);
  u += 0x7FFFu + ((u >> 16) & 1u);
  return (unsigned short)(u >> 16);
}
__device__ __forceinline__ float bf2f(unsigned short h){
  return __uint_as_float(((unsigned)h) << 16);
}
__device__ __forceinline__ void gload16(const unsigned short* g, unsigned short* l){
  __builtin_amdgcn_global_load_lds(
      (const __attribute__((address_space(1))) unsigned int*)g,
      (__attribute__((address_space(3))) unsigned int*)l, 16, 0, 0);
}

__device__ __forceinline__ float red256(float v, float* sh){
  int t = threadIdx.x;
  sh[t] = v; __syncthreads();
  for(int s = 128; s > 0; s >>= 1){ if(t < s) sh[t] += sh[t+s]; __syncthreads(); }
  float r = sh[0]; __syncthreads();
  return r;
}

// ---------------- init ----------------
__global__ void k_init(int* counts, unsigned* enc){
  int t = threadIdx.x;
  if(t < CDIM) counts[t] = 0;
  if(t == 0){ enc[0] = 0xFFFFFFFFu; enc[1] = 0u; }
}

// ---------------- column sums, 512 chunks x 43 rows ----------------
__global__ __launch_bounds__(256) void k_colmean1(const float* __restrict__ X, float* __restrict__ pbuf){
  int b = blockIdx.x, t = threadIdx.x;
  int n0 = b * 43, n1 = n0 + 43; if(n1 > NTOT) n1 = NTOT;
  float s0 = 0.f, s1 = 0.f, s2 = 0.f;
  for(int n = n0; n < n1; ++n){
    const float* row = X + (size_t)n * DIM;
    s0 += row[t]; s1 += row[t + 256]; s2 += row[t + 512];
  }
  float* pb = pbuf + (size_t)b * DIM;
  pb[t] = s0; pb[t + 256] = s1; pb[t + 512] = s2;
}

// ---------------- mean + wv init + parts (3 blocks) ----------------
__global__ __launch_bounds__(256) void k_meanred(const float* __restrict__ pbuf,
    float* __restrict__ meanv, float* __restrict__ wvb, float* __restrict__ parts){
  __shared__ float sh[256];
  int b = blockIdx.x, t = threadIdx.x;
  int col = b * 256 + t;
  float s = 0.f;
  for(int ch = 0; ch < 512; ++ch) s += pbuf[ch * DIM + col];
  float m = s / 21904.0f;
  meanv[col] = m;
  const float v0 = 0.036084391824351615f;   // 1/sqrt(768)
  wvb[col] = v0;
  float sq = red256(v0 * v0, sh);
  float md = red256(m * v0, sh);
  if(t == 0){ parts[b] = sq; parts[8 + b] = md; }
}

// ---------------- power-iteration pass: pbuf/subuf partials of Xc^T(Xc v) ----------------
__global__ __launch_bounds__(256) void k_pcapass(const float* __restrict__ X,
    const float* __restrict__ wvb, const float* __restrict__ parts,
    float* __restrict__ pbuf, float* __restrict__ subuf){
  __shared__ float shacc[4][DIM];
  __shared__ float shsu[4];
  int t = threadIdx.x, w = t >> 6, l = t & 63;
  float nrm = sqrtf(parts[0] + parts[1] + parts[2]);
  float invD = 1.0f / (nrm + 1e-12f);
  float mvr = parts[8] + parts[9] + parts[10];
  const float4* v4 = (const float4*)(wvb + l * 12);
  float4 v0 = v4[0], v1 = v4[1], v2 = v4[2];
  float4 a0 = {0,0,0,0}, a1 = {0,0,0,0}, a2 = {0,0,0,0};
  float su = 0.f;
  for(int n = blockIdx.x * 4 + w; n < NTOT; n += 2048){
    const float4* x4 = (const float4*)(X + (size_t)n * DIM + l * 12);
    float4 x0 = x4[0], x1 = x4[1], x2 = x4[2];
    float tp = x0.x*v0.x + x0.y*v0.y + x0.z*v0.z + x0.w*v0.w
             + x1.x*v1.x + x1.y*v1.y + x1.z*v1.z + x1.w*v1.w
             + x2.x*v2.x + x2.y*v2.y + x2.z*v2.z + x2.w*v2.w;
    #pragma unroll
    for(int o = 32; o > 0; o >>= 1) tp += __shfl_xor(tp, o);
    tp = (tp - mvr) * invD;
    a0.x += tp*x0.x; a0.y += tp*x0.y; a0.z += tp*x0.z; a0.w += tp*x0.w;
    a1.x += tp*x1.x; a1.y += tp*x1.y; a1.z += tp*x1.z; a1.w += tp*x1.w;
    a2.x += tp*x2.x; a2.y += tp*x2.y; a2.z += tp*x2.z; a2.w += tp*x2.w;
    if(l == 0) su += tp;
  }
  float4* sh4 = (float4*)&shacc[w][l * 12];
  sh4[0] = a0; sh4[1] = a1; sh4[2] = a2;
  if(l == 0) shsu[w] = su;
  __syncthreads();
  for(int c = t; c < DIM; c += 256)
    pbuf[blockIdx.x * DIM + c] = shacc[0][c] + shacc[1][c] + shacc[2][c] + shacc[3][c];
  if(t == 0) subuf[blockIdx.x] = shsu[0] + shsu[1] + shsu[2] + shsu[3];
}

// ---------------- reduce partials -> new wv + parts (3 blocks) ----------------
__global__ __launch_bounds__(256) void k_pcared(const float* __restrict__ pbuf,
    const float* __restrict__ subuf, const float* __restrict__ meanv,
    float* __restrict__ wvb, float* __restrict__ parts){
  __shared__ float sh[256];
  int b = blockIdx.x, t = threadIdx.x;
  float su = red256(subuf[t] + subuf[t + 256], sh);
  int col = b * 256 + t;
  float s = 0.f;
  for(int ch = 0; ch < 512; ++ch) s += pbuf[ch * DIM + col];
  float wvn = s - meanv[col] * su;
  wvb[col] = wvn;
  float sq = red256(wvn * wvn, sh);
  float md = red256(meanv[col] * wvn, sh);
  if(t == 0){ parts[b] = sq; parts[8 + b] = md; }
}

// ---------------- final u = Xc v, plus min/max ----------------
__global__ __launch_bounds__(256) void k_ufinal(const float* __restrict__ X,
    const float* __restrict__ wvb, const float* __restrict__ parts,
    float* __restrict__ u, unsigned* __restrict__ enc){
  __shared__ float smn[4], smx[4];
  int t = threadIdx.x, w = t >> 6, l = t & 63;
  float nrm = sqrtf(parts[0] + parts[1] + parts[2]);
  float invD = 1.0f / (nrm + 1e-12f);
  float mvr = parts[8] + parts[9] + parts[10];
  const float4* v4 = (const float4*)(wvb + l * 12);
  float4 v0 = v4[0], v1 = v4[1], v2 = v4[2];
  float lmn = 3.4e38f, lmx = -3.4e38f;
  for(int n = blockIdx.x * 4 + w; n < NTOT; n += 2048){
    const float4* x4 = (const float4*)(X + (size_t)n * DIM + l * 12);
    float4 x0 = x4[0], x1 = x4[1], x2 = x4[2];
    float tp = x0.x*v0.x + x0.y*v0.y + x0.z*v0.z + x0.w*v0.w
             + x1.x*v1.x + x1.y*v1.y + x1.z*v1.z + x1.w*v1.w
             + x2.x*v2.x + x2.y*v2.y + x2.z*v2.z + x2.w*v2.w;
    #pragma unroll
    for(int o = 32; o > 0; o >>= 1) tp += __shfl_xor(tp, o);
    tp = (tp - mvr) * invD;
    if(l == 0){ u[n] = tp; lmn = fminf(lmn, tp); lmx = fmaxf(lmx, tp); }
  }
  if(l == 0){ smn[w] = lmn; smx[w] = lmx; }
  __syncthreads();
  if(t == 0){
    float mn = fminf(fminf(smn[0], smn[1]), fminf(smn[2], smn[3]));
    float mx = fmaxf(fmaxf(smx[0], smx[1]), fmaxf(smx[2], smx[3]));
    atomicMin(&enc[0], encf(mn));
    atomicMax(&enc[1], encf(mx));
  }
}

// ---------------- pseudo labels ----------------
__global__ __launch_bounds__(256) void k_pseudo(const float* __restrict__ u,
    const unsigned* __restrict__ enc, const int* __restrict__ labels,
    int* __restrict__ pl, float* __restrict__ pseudo_out,
    float* __restrict__ assign_out, int* __restrict__ counts){
  int n = blockIdx.x * 256 + threadIdx.x;
  if(n >= NTOT) return;
  float mn = decf(enc[0]), mx = decf(enc[1]);
  float us = (u[n] - mn) / (mx - mn);
  int b = n / NPATCH;
  int p = (us <= 0.5f) ? labels[b] : NCLS;
  pl[n] = p;
  pseudo_out[n] = (float)p;
  assign_out[n] = -1.0f;
  atomicAdd(&counts[p], 1);
}

__global__ void k_rank(const int* __restrict__ counts, int* __restrict__ rankv){
  if(threadIdx.x == 0){
    int r = 0;
    for(int c = 0; c < NCLS; ++c){
      if(counts[c] > 0){ rankv[c] = r; r++; } else rankv[c] = 0;
    }
  }
}

// ---------------- row norms (fallback path) ----------------
__global__ __launch_bounds__(256) void k_rnorm(const float* __restrict__ X, float* __restrict__ rinv){
  int t = threadIdx.x, w = t >> 6, l = t & 63;
  int n = blockIdx.x * 4 + w;
  if(n >= NTOT) return;
  const float4* x4 = (const float4*)(X + (size_t)n * DIM + l * 12);
  float4 x0 = x4[0], x1 = x4[1], x2 = x4[2];
  float s = x0.x*x0.x + x0.y*x0.y + x0.z*x0.z + x0.w*x0.w
          + x1.x*x1.x + x1.y*x1.y + x1.z*x1.z + x1.w*x1.w
          + x2.x*x2.x + x2.y*x2.y + x2.z*x2.z + x2.w*x2.w;
  #pragma unroll
  for(int o = 32; o > 0; o >>= 1) s += __shfl_xor(s, o);
  if(l == 0) rinv[n] = 1.0f / (sqrtf(s) + 1e-12f);
}

// ---------------- row norm + bf16 hi/lo split of ptn = X*rinv (padded to MPAD) ----------------
__global__ __launch_bounds__(256) void k_prep_a(const float* __restrict__ X,
    float* __restrict__ rinv, unsigned short* __restrict__ Ahi, unsigned short* __restrict__ Alo){
  int t = threadIdx.x, w = t >> 6, l = t & 63;
  int n = blockIdx.x * 4 + w;
  if(n >= MPAD) return;
  size_t off = (size_t)n * DIM + l * 12;
  if(n >= NTOT){
    ushort4 z = make_ushort4(0, 0, 0, 0);
    #pragma unroll
    for(int j = 0; j < 3; ++j){
      *(ushort4*)(Ahi + off + j * 4) = z;
      *(ushort4*)(Alo + off + j * 4) = z;
    }
    return;
  }
  const float4* x4 = (const float4*)(X + off);
  float4 x0 = x4[0], x1 = x4[1], x2 = x4[2];
  float s = x0.x*x0.x + x0.y*x0.y + x0.z*x0.z + x0.w*x0.w
          + x1.x*x1.x + x1.y*x1.y + x1.z*x1.z + x1.w*x1.w
          + x2.x*x2.x + x2.y*x2.y + x2.z*x2.z + x2.w*x2.w;
  #pragma unroll
  for(int o = 32; o > 0; o >>= 1) s += __shfl_xor(s, o);
  float rv = 1.0f / (sqrtf(s) + 1e-12f);
  if(l == 0) rinv[n] = rv;
  float xs[12] = {x0.x*rv, x0.y*rv, x0.z*rv, x0.w*rv,
                  x1.x*rv, x1.y*rv, x1.z*rv, x1.w*rv,
                  x2.x*rv, x2.y*rv, x2.z*rv, x2.w*rv};
  unsigned short hi[12], lo[12];
  #pragma unroll
  for(int j = 0; j < 12; ++j){
    hi[j] = f2bf(xs[j]);
    lo[j] = f2bf(xs[j] - bf2f(hi[j]));
  }
  #pragma unroll
  for(int j = 0; j < 3; ++j){
    *(ushort4*)(Ahi + off + j * 4) = make_ushort4(hi[j*4], hi[j*4+1], hi[j*4+2], hi[j*4+3]);
    *(ushort4*)(Alo + off + j * 4) = make_ushort4(lo[j*4], lo[j*4+1], lo[j*4+2], lo[j*4+3]);
  }
}

// ---------------- bf16 hi/lo split of Bmat (padded to 1024 rows) ----------------
__global__ __launch_bounds__(256) void k_prep_b(const float* __restrict__ Bmat,
    unsigned short* __restrict__ Bhi, unsigned short* __restrict__ Blo){
  int t = threadIdx.x, w = t >> 6, l = t & 63;
  int r = blockIdx.x * 4 + w;
  if(r >= 1024) return;
  size_t off = (size_t)r * DIM + l * 12;
  unsigned short hi[12], lo[12];
  if(r < NCK){
    const float4* x4 = (const float4*)(Bmat + off);
    float4 x0 = x4[0], x1 = x4[1], x2 = x4[2];
    float xs[12] = {x0.x, x0.y, x0.z, x0.w, x1.x, x1.y, x1.z, x1.w, x2.x, x2.y, x2.z, x2.w};
    #pragma unroll
    for(int j = 0; j < 12; ++j){
      hi[j] = f2bf(xs[j]);
      lo[j] = f2bf(xs[j] - bf2f(hi[j]));
    }
  } else {
    #pragma unroll
    for(int j = 0; j < 12; ++j){ hi[j] = 0; lo[j] = 0; }
  }
  #pragma unroll
  for(int j = 0; j < 3; ++j){
    *(ushort4*)(Bhi + off + j * 4) = make_ushort4(hi[j*4], hi[j*4+1], hi[j*4+2], hi[j*4+3]);
    *(ushort4*)(Blo + off + j * 4) = make_ushort4(lo[j*4], lo[j*4+1], lo[j*4+2], lo[j*4+3]);
  }
}

// ---------------- normalized prototypes + bias2 ----------------
__global__ __launch_bounds__(256) void k_protn(const float* __restrict__ P,
    const float* __restrict__ bvec, float* __restrict__ protn, float* __restrict__ bias2){
  int t = threadIdx.x, w = t >> 6, l = t & 63;
  int r = blockIdx.x * 4 + w;
  if(r >= NCK) return;
  const float4* x4 = (const float4*)(P + (size_t)r * DIM + l * 12);
  float4 x0 = x4[0], x1 = x4[1], x2 = x4[2];
  float s = x0.x*x0.x + x0.y*x0.y + x0.z*x0.z + x0.w*x0.w
          + x1.x*x1.x + x1.y*x1.y + x1.z*x1.z + x1.w*x1.w
          + x2.x*x2.x + x2.y*x2.y + x2.z*x2.z + x2.w*x2.w;
  #pragma unroll
  for(int o = 32; o > 0; o >>= 1) s += __shfl_xor(s, o);
  float rv = 1.0f / (sqrtf(s) + 1e-12f);
  x0.x *= rv; x0.y *= rv; x0.z *= rv; x0.w *= rv;
  x1.x *= rv; x1.y *= rv; x1.z *= rv; x1.w *= rv;
  x2.x *= rv; x2.y *= rv; x2.z *= rv; x2.w *= rv;
  float4* o4 = (float4*)(protn + (size_t)r * DIM + l * 12);
  o4[0] = x0; o4[1] = x1; o4[2] = x2;
  const float4* b4 = (const float4*)(bvec + l * 12);
  float4 b0 = b4[0], b1 = b4[1], b2 = b4[2];
  float bb = b0.x*x0.x + b0.y*x0.y + b0.z*x0.z + b0.w*x0.w
           + b1.x*x1.x + b1.y*x1.y + b1.z*x1.z + b1.w*x1.w
           + b2.x*x2.x + b2.y*x2.y + b2.z*x2.z + b2.w*x2.w;
  #pragma unroll
  for(int o = 32; o > 0; o >>= 1) bb += __shfl_xor(bb, o);
  if(l == 0) bias2[r] = bb;
}

// ---------------- f32 NT GEMM (small Bmat compute + fallback) ----------------
template<int HAS_SCALE, int HAS_BIAS, int HAS_ADD>
__global__ __launch_bounds__(256) void k_gemm_nt(const float* __restrict__ A,
    const float* __restrict__ B, float* __restrict__ C,
    const float* __restrict__ rowScale, const float* __restrict__ colBias,
    const float* __restrict__ addMat, int M, int N, int K){
  __shared__ float As[32][72];
  __shared__ float Bs[32][72];
  int t = threadIdx.x;
  int m0 = blockIdx.y * 64, n0 = blockIdx.x * 64;
  int srow = t >> 2, skq = (t & 3) * 8;
  int ty = t >> 4, tx = t & 15;
  int i0 = ty * 4, j0 = tx * 4;
  float acc[4][4] = {};
  int gra = m0 + srow; bool va = gra < M;
  int grb = n0 + srow; bool vb = grb < N;
  float scale = 1.0f;
  if(HAS_SCALE && va) scale = rowScale[gra];
  const float* Aptr = A + (size_t)gra * K + skq;
  const float* Bptr = B + (size_t)grb * K + skq;
  for(int k0 = 0; k0 < K; k0 += 32){
    float4 a0 = {0,0,0,0}, a1 = {0,0,0,0}, b0 = {0,0,0,0}, b1 = {0,0,0,0};
    if(va){ a0 = *(const float4*)(Aptr + k0); a1 = *(const float4*)(Aptr + k0 + 4); }
    if(vb){ b0 = *(const float4*)(Bptr + k0); b1 = *(const float4*)(Bptr + k0 + 4); }
    if(HAS_SCALE){
      a0.x *= scale; a0.y *= scale; a0.z *= scale; a0.w *= scale;
      a1.x *= scale; a1.y *= scale; a1.z *= scale; a1.w *= scale;
    }
    __syncthreads();
    As[skq+0][srow] = a0.x; As[skq+1][srow] = a0.y; As[skq+2][srow] = a0.z; As[skq+3][srow] = a0.w;
    As[skq+4][srow] = a1.x; As[skq+5][srow] = a1.y; As[skq+6][srow] = a1.z; As[skq+7][srow] = a1.w;
    Bs[skq+0][srow] = b0.x; Bs[skq+1][srow] = b0.y; Bs[skq+2][srow] = b0.z; Bs[skq+3][srow] = b0.w;
    Bs[skq+4][srow] = b1.x; Bs[skq+5][srow] = b1.y; Bs[skq+6][srow] = b1.z; Bs[skq+7][srow] = b1.w;
    __syncthreads();
    #pragma unroll
    for(int kk = 0; kk < 32; ++kk){
      float4 avv = *(const float4*)&As[kk][i0];
      float4 bvv = *(const float4*)&Bs[kk][j0];
      float a_[4] = {avv.x, avv.y, avv.z, avv.w};
      float b_[4] = {bvv.x, bvv.y, bvv.z, bvv.w};
      #pragma unroll
      for(int i = 0; i < 4; ++i)
        #pragma unroll
        for(int j = 0; j < 4; ++j)
          acc[i][j] += a_[i] * b_[j];
    }
  }
  #pragma unroll
  for(int i = 0; i < 4; ++i){
    int gr = m0 + i0 + i; if(gr >= M) continue;
    #pragma unroll
    for(int j = 0; j < 4; ++j){
      int gc = n0 + j0 + j; if(gc >= N) continue;
      float v2 = acc[i][j];
      if(HAS_BIAS) v2 += colBias[gc];
      if(HAS_ADD) v2 += addMat[(size_t)gr * N + gc];
      C[(size_t)gr * N + gc] = v2;
    }
  }
}

// ---------------- MFMA split-bf16 main GEMM (global_load_lds staging) ----------------
// LDS regions (ushort idx): Ahi 0, Alo 4096, Bhi 8192, Blo 12288.
// Region layout: [128 rows][4 pos][8 bf16], pos = q ^ ((row>>1)&3)  (bank swizzle).
__global__ __launch_bounds__(256) void k_gemm_mfma(
    const unsigned short* __restrict__ Ahi, const unsigned short* __restrict__ Alo,
    const unsigned short* __restrict__ Bhi, const unsigned short* __restrict__ Blo,
    const float* __restrict__ bias2, float* __restrict__ C){
  __shared__ __align__(16) unsigned short lds[16384];   // 32 KB
  int h = blockIdx.x;
  int nt = h & 7, mt = h >> 3;
  int m0 = mt * 128, n0 = nt * 128;
  int t = threadIdx.x;
  int w = t >> 6, l = t & 63;
  int wm = w & 1, wn = w >> 1;
  int lr = l & 15, lk = l >> 4;
  int srow = l >> 2, sp = l & 3;         // staging: 4 lanes per row

  const unsigned short* gsrc;
  int rbase;
  if(w == 0){ gsrc = Ahi; rbase = m0; }
  else if(w == 1){ gsrc = Alo; rbase = m0; }
  else if(w == 2){ gsrc = Bhi; rbase = n0; }
  else          { gsrc = Blo; rbase = n0; }

  f32x4v acc[4][4];
  #pragma unroll
  for(int i = 0; i < 4; ++i)
    #pragma unroll
    for(int j = 0; j < 4; ++j) acc[i][j] = (f32x4v){0.f, 0.f, 0.f, 0.f};

  // precompute swizzled read offsets (ushort units)
  int aofs[4], bofs[4];
  #pragma unroll
  for(int f = 0; f < 4; ++f){
    int ar = wm * 64 + f * 16 + lr;
    aofs[f] = ar * 32 + (lk ^ ((ar >> 1) & 3)) * 8;
    int bc = wn * 64 + f * 16 + lr;
    bofs[f] = bc * 32 + (lk ^ ((bc >> 1) & 3)) * 8;
  }

  for(int k0 = 0; k0 < DIM; k0 += 32){
    #pragma unroll
    for(int c = 0; c < 8; ++c){
      int row = c * 16 + srow;
      int q = sp ^ ((row >> 1) & 3);
      const unsigned short* gp = gsrc + (size_t)(rbase + row) * DIM + k0 + q * 8;
      gload16(gp, lds + w * 4096 + c * 512);
    }
    __syncthreads();
    bf16x8 ah[4], al[4], bh[4], bl[4];
    #pragma unroll
    for(int f = 0; f < 4; ++f){
      ah[f] = *(const bf16x8*)&lds[aofs[f]];
      al[f] = *(const bf16x8*)&lds[4096 + aofs[f]];
      bh[f] = *(const bf16x8*)&lds[8192 + bofs[f]];
      bl[f] = *(const bf16x8*)&lds[12288 + bofs[f]];
    }
    #pragma unroll
    for(int i = 0; i < 4; ++i)
      #pragma unroll
      for(int j = 0; j < 4; ++j){
        acc[i][j] = __builtin_amdgcn_mfma_f32_16x16x32_bf16(ah[i], bh[j], acc[i][j], 0, 0, 0);
        acc[i][j] = __builtin_amdgcn_mfma_f32_16x16x32_bf16(ah[i], bl[j], acc[i][j], 0, 0, 0);
        acc[i][j] = __builtin_amdgcn_mfma_f32_16x16x32_bf16(al[i], bh[j], acc[i][j], 0, 0, 0);
      }
    __syncthreads();
  }
  #pragma unroll
  for(int i = 0; i < 4; ++i){
    #pragma unroll
    for(int j = 0; j < 4; ++j){
      int col = n0 + wn * 64 + j * 16 + lr;
      if(col >= NCK) continue;
      float bv = bias2[col];
      #pragma unroll
      for(int r2 = 0; r2 < 4; ++r2){
        int row = m0 + wm * 64 + i * 16 + lk * 4 + r2;
        if(row < NTOT) C[(size_t)row * NCK + col] = acc[i][j][r2] + bv;
      }
    }
  }
}

// ---------------- per-class masked Sinkhorn ----------------
__global__ __launch_bounds__(256) void k_sinkhorn(const float* __restrict__ logits,
    const int* __restrict__ pl, const int* __restrict__ counts, const int* __restrict__ rankv,
    const int* __restrict__ labels, float* __restrict__ Aw, float* __restrict__ assign_out){
  int c = blockIdx.x;
  int NcI = counts[c];
  if(NcI == 0) return;
  __shared__ int imgs[BIMG];
  __shared__ int nimgS;
  __shared__ float sh[256];
  int t = threadIdx.x;
  if(t == 0){
    int ni = 0;
    for(int b = 0; b < BIMG; ++b) if(labels[b] == c) imgs[ni++] = b;
    nimgS = ni;
  }
  __syncthreads();
  int tot = nimgS * NPATCH;
  float Ncf = (float)NcI;
  float invNc = 1.0f / Ncf;

  float sp = 0.f;
  for(int ii = t; ii < tot; ii += 256){
    int n = imgs[ii / NPATCH] * NPATCH + (ii % NPATCH);
    if(pl[n] != c) continue;
    const float* lg = logits + (size_t)n * NCK + c * KP;
    float* aw = Aw + (size_t)n * KP;
    float l0 = expf(lg[0] / 0.05f), l1 = expf(lg[1] / 0.05f), l2 = expf(lg[2] / 0.05f),
          l3 = expf(lg[3] / 0.05f), l4 = expf(lg[4] / 0.05f);
    aw[0] = l0; aw[1] = l1; aw[2] = l2; aw[3] = l3; aw[4] = l4;
    sp += l0 + l1 + l2 + l3 + l4;
  }
  float S = red256(sp, sh);
  float sc = 1.0f / (S + 1e-16f);

  float cs0 = 0, cs1 = 0, cs2 = 0, cs3 = 0, cs4 = 0;
  for(int ii = t; ii < tot; ii += 256){
    int n = imgs[ii / NPATCH] * NPATCH + (ii % NPATCH);
    if(pl[n] != c) continue;
    float* aw = Aw + (size_t)n * KP;
    float l0 = aw[0]*sc, l1 = aw[1]*sc, l2 = aw[2]*sc, l3 = aw[3]*sc, l4 = aw[4]*sc;
    aw[0] = l0; aw[1] = l1; aw[2] = l2; aw[3] = l3; aw[4] = l4;
    cs0 += l0; cs1 += l1; cs2 += l2; cs3 += l3; cs4 += l4;
  }
  cs0 = red256(cs0, sh); cs1 = red256(cs1, sh); cs2 = red256(cs2, sh);
  cs3 = red256(cs3, sh); cs4 = red256(cs4, sh);

  for(int it = 0; it < 3; ++it){
    float m0 = 1.0f/(cs0+1e-16f), m1 = 1.0f/(cs1+1e-16f), m2 = 1.0f/(cs2+1e-16f),
          m3 = 1.0f/(cs3+1e-16f), m4 = 1.0f/(cs4+1e-16f);
    bool last = (it == 2);
    float n0 = 0, n1 = 0, n2 = 0, n3 = 0, n4 = 0;
    for(int ii = t; ii < tot; ii += 256){
      int n = imgs[ii / NPATCH] * NPATCH + (ii % NPATCH);
      if(pl[n] != c) continue;
      float* aw = Aw + (size_t)n * KP;
      float l0 = aw[0]*m0*0.2f, l1 = aw[1]*m1*0.2f, l2 = aw[2]*m2*0.2f,
            l3 = aw[3]*m3*0.2f, l4 = aw[4]*m4*0.2f;
      float rs = l0 + l1 + l2 + l3 + l4;
      float rw = 1.0f / (rs + 1e-16f);
      if(last){
        l0 *= rw; l1 *= rw; l2 *= rw; l3 *= rw; l4 *= rw;
        aw[0] = l0; aw[1] = l1; aw[2] = l2; aw[3] = l3; aw[4] = l4;
        int am = 0; float bv = l0;
        if(l1 > bv){ bv = l1; am = 1; }
        if(l2 > bv){ bv = l2; am = 2; }
        if(l3 > bv){ bv = l3; am = 3; }
        if(l4 > bv){ bv = l4; am = 4; }
        assign_out[n] = (float)(am + KP * rankv[c]);
      } else {
        float w2 = rw * invNc;
        l0 *= w2; l1 *= w2; l2 *= w2; l3 *= w2; l4 *= w2;
        aw[0] = l0; aw[1] = l1; aw[2] = l2; aw[3] = l3; aw[4] = l4;
        n0 += l0; n1 += l1; n2 += l2; n3 += l3; n4 += l4;
      }
    }
    if(!last){
      cs0 = red256(n0, sh); cs1 = red256(n1, sh); cs2 = red256(n2, sh);
      cs3 = red256(n3, sh); cs4 = red256(n4, sh);
    }
  }
}

// ---------------- P_new partial sums ----------------
__global__ __launch_bounds__(256) void k_pnew_part(const float* __restrict__ X,
    const float* __restrict__ rinv, const float* __restrict__ Aw,
    const int* __restrict__ pl, const int* __restrict__ labels,
    float* __restrict__ part){
  int b = blockIdx.y, ch = blockIdx.x;
  int c = labels[b];
  int t = threadIdx.x;
  int j0 = ch * 86, j1 = j0 + 86; if(j1 > NPATCH) j1 = NPATCH;
  float acc[3][5] = {};
  for(int j = j0; j < j1; ++j){
    int n = b * NPATCH + j;
    if(pl[n] != c) continue;
    const float* aw = Aw + (size_t)n * KP;
    float a0 = aw[0], a1 = aw[1], a2 = aw[2], a3 = aw[3], a4 = aw[4];
    float rv = rinv[n];
    #pragma unroll
    for(int dj = 0; dj < 3; ++dj){
      float x = X[(size_t)n * DIM + t + dj * 256] * rv;
      acc[dj][0] += a0 * x; acc[dj][1] += a1 * x; acc[dj][2] += a2 * x;
      acc[dj][3] += a3 * x; acc[dj][4] += a4 * x;
    }
  }
  float* po = part + ((size_t)(b * PCH + ch)) * KP * DIM;
  #pragma unroll
  for(int k = 0; k < 5; ++k)
    #pragma unroll
    for(int dj = 0; dj < 3; ++dj)
      po[k * DIM + t + dj * 256] = acc[dj][k];
}

// ---------------- P_new final ----------------
__global__ __launch_bounds__(256) void k_pnew_fin(const float* __restrict__ P,
    const float* __restrict__ part, const int* __restrict__ counts,
    const int* __restrict__ labels, float* __restrict__ out_np){
  int c = blockIdx.x;
  int t = threadIdx.x;
  bool pres = (c < NCLS) && (counts[c] > 0);
  const float* Pc = P + (size_t)c * KP * DIM;
  float* Oc = out_np + (size_t)c * KP * DIM;
  if(!pres){
    for(int i = t; i < KP * DIM; i += 256) Oc[i] = Pc[i];
    return;
  }
  __shared__ int imgs[BIMG];
  __shared__ int nimgS;
  if(t == 0){
    int ni = 0;
    for(int b = 0; b < BIMG; ++b) if(labels[b] == c) imgs[ni++] = b;
    nimgS = ni;
  }
  __syncthreads();
  int ni = nimgS;
  for(int i = t; i < KP * DIM; i += 256){
    float s = 0.f;
    for(int q = 0; q < ni; ++q){
      const float* pb = part + ((size_t)(imgs[q] * PCH)) * KP * DIM + i;
      for(int ch = 0; ch < PCH; ++ch) s += pb[(size_t)ch * KP * DIM];
    }
    Oc[i] = 0.99f * Pc[i] + 0.01f * s;
  }
}

// ---------------- pooled stage 1 ----------------
__global__ __launch_bounds__(256) void k_pool1(const float* __restrict__ logits,
    float* __restrict__ poolPart){
  int b = blockIdx.y, ch = blockIdx.x;
  int t = threadIdx.x;
  int j0 = ch * 43, j1 = j0 + 43; if(j1 > NPATCH) j1 = NPATCH;
  float a0 = 0, a1 = 0, a2 = 0, a3 = 0;
  for(int j = j0; j < j1; ++j){
    const float* row = logits + ((size_t)(b * NPATCH + j)) * NCK;
    a0 += row[t]; a1 += row[t + 256]; a2 += row[t + 512];
    if(t < 237) a3 += row[t + 768];
  }
  float* po = poolPart + ((size_t)(b * QCH + ch)) * 1024;
  po[t] = a0; po[t + 256] = a1; po[t + 512] = a2;
  if(t < 237) po[t + 768] = a3;
}

// ---------------- pooled stage 2 ----------------
__global__ __launch_bounds__(256) void k_pool2(const float* __restrict__ poolPart,
    float* __restrict__ pooled){
  int b = blockIdx.x;
  int t = threadIdx.x;
  float s0 = 0, s1 = 0, s2 = 0, s3 = 0;
  const float* pb = poolPart + ((size_t)(b * QCH)) * 1024;
  for(int ch = 0; ch < QCH; ++ch){
    const float* p = pb + (size_t)ch * 1024;
    s0 += p[t]; s1 += p[t + 256]; s2 += p[t + 512];
    if(t < 237) s3 += p[t + 768];
  }
  float* o = pooled + (size_t)b * NCK;
  o[t] = s0 / 1369.0f; o[t + 256] = s1 / 1369.0f; o[t + 512] = s2 / 1369.0f;
  if(t < 237) o[t + 768] = s3 / 1369.0f;
}

// ---------------- class logits (sa head) ----------------
__global__ __launch_bounds__(256) void k_cls(const float* __restrict__ pooled,
    const float* __restrict__ sa, float* __restrict__ out){
  int b = blockIdx.x;
  int i = threadIdx.x;
  if(i >= NCLS) return;
  float s0 = sa[i*5+0], s1 = sa[i*5+1], s2 = sa[i*5+2], s3 = sa[i*5+3], s4 = sa[i*5+4];
  float mx = fmaxf(fmaxf(fmaxf(s0, s1), fmaxf(s2, s3)), s4);
  float e0 = expf(s0 - mx), e1 = expf(s1 - mx), e2 = expf(s2 - mx),
        e3 = expf(s3 - mx), e4 = expf(s4 - mx);
  float se = e0 + e1 + e2 + e3 + e4;
  float iv = 5.0f / se;
  const float* p = pooled + (size_t)b * NCK + i * KP;
  float cl = p[0]*e0*iv + p[1]*e1*iv + p[2]*e2*iv + p[3]*e3*iv + p[4]*e4*iv;
  out[b * NCLS + i] = cl;
}

extern "C" void kernel_launch(void* const* d_in, const int* in_sizes, int n_in,
                              void* d_out, int out_size, void* d_ws, size_t ws_size,
                              hipStream_t stream){
  const float* X      = (const float*)d_in[0];
  const int*   labels = (const int*)d_in[1];
  const float* P      = (const float*)d_in[2];
  const float* W      = (const float*)d_in[3];
  const float* bvec   = (const float*)d_in[4];
  const float* sa     = (const float*)d_in[5];

  float* out        = (float*)d_out;
  float* out_cls    = out;
  float* out_logits = out + 3200;
  float* out_pooled = out_logits + (size_t)NTOT * NCK;
  float* out_assign = out_pooled + BIMG * NCK;
  float* out_np     = out_assign + NTOT;
  float* out_pseudo = out_np + (size_t)CDIM * KP * DIM;

  const size_t AHI_F = (size_t)MPAD * DIM / 2;   // ushort array in float units
  const size_t BHI_F = (size_t)1024 * DIM / 2;
  const size_t MFMA_F = 2 * AHI_F + 2 * BHI_F;
  const size_t BASE_F = 3700000;
  bool use_mfma = ws_size >= (MFMA_F + BASE_F) * sizeof(float);

  float* ws = (float*)d_ws;
  unsigned short* Ahi = (unsigned short*)ws;
  unsigned short* Alo = (unsigned short*)(ws + AHI_F);
  unsigned short* Bhi = (unsigned short*)(ws + 2 * AHI_F);
  unsigned short* Blo = (unsigned short*)(ws + 2 * AHI_F + BHI_F);
  float* base = use_mfma ? (ws + MFMA_F) : ws;

  float* protn  = base;
  float* Bmat   = protn + (size_t)NCK * DIM;
  float* bias2  = Bmat + (size_t)NCK * DIM;
  float* rinv   = bias2 + 1024;
  float* uvec   = rinv + NTOT;
  float* Aw     = uvec + NTOT;
  float* meanv  = Aw + (size_t)NTOT * KP;
  float* wvb    = meanv + DIM;
  float* pbuf   = wvb + DIM;
  float* subuf  = pbuf + 512 * DIM;
  float* parts  = subuf + 512;
  float* scal   = parts + 16;
  int*   pli    = (int*)(scal + 8);
  int*   counts = pli + NTOT;
  int*   rankv  = counts + 256;
  float* pnewP  = (float*)(rankv + 256);
  float* poolP  = pnewP + (size_t)BIMG * PCH * KP * DIM;
  unsigned* enc = (unsigned*)(scal + 1);

  k_init<<<1, 256, 0, stream>>>(counts, enc);
  k_colmean1<<<512, 256, 0, stream>>>(X, pbuf);
  k_meanred<<<3, 256, 0, stream>>>(pbuf, meanv, wvb, parts);
  for(int i = 0; i < 10; ++i){
    k_pcapass<<<512, 256, 0, stream>>>(X, wvb, parts, pbuf, subuf);
    k_pcared<<<3, 256, 0, stream>>>(pbuf, subuf, meanv, wvb, parts);
  }
  k_ufinal<<<512, 256, 0, stream>>>(X, wvb, parts, uvec, enc);
  k_pseudo<<<86, 256, 0, stream>>>(uvec, enc, labels, pli, out_pseudo, out_assign, counts);
  k_rank<<<1, 64, 0, stream>>>(counts, rankv);
  if(use_mfma){
    k_prep_a<<<MPAD / 4, 256, 0, stream>>>(X, rinv, Ahi, Alo);
  } else {
    k_rnorm<<<5476, 256, 0, stream>>>(X, rinv);
  }
  k_protn<<<252, 256, 0, stream>>>(P, bvec, protn, bias2);
  k_gemm_nt<0, 0, 1><<<dim3(12, 16), 256, 0, stream>>>(protn, W, Bmat, nullptr, nullptr, protn, NCK, DIM, DIM);
  if(use_mfma){
    k_prep_b<<<256, 256, 0, stream>>>(Bmat, Bhi, Blo);
    k_gemm_mfma<<<1376, 256, 0, stream>>>(Ahi, Alo, Bhi, Blo, bias2, out_logits);
  } else {
    k_gemm_nt<1, 1, 0><<<dim3(16, 343), 256, 0, stream>>>(X, Bmat, out_logits, rinv, bias2, nullptr, NTOT, NCK, DIM);
  }
  k_sinkhorn<<<NCLS, 256, 0, stream>>>(out_logits, pli, counts, rankv, labels, Aw, out_assign);
  k_pnew_part<<<dim3(PCH, BIMG), 256, 0, stream>>>(X, rinv, Aw, pli, labels, pnewP);
  k_pnew_fin<<<CDIM, 256, 0, stream>>>(P, pnewP, counts, labels, out_np);
  k_pool1<<<dim3(QCH, BIMG), 256, 0, stream>>>(out_logits, poolP);
  k_pool2<<<BIMG, 256, 0, stream>>>(poolP, out_pooled);
  k_cls<<<BIMG, 256, 0, stream>>>(out_pooled, sa, out_cls);
}